// Round 1
// baseline (2128.085 us; speedup 1.0000x reference)
//
#include <hip/hip_runtime.h>
#include <math.h>

// Problem constants (match reference)
#define NN 20000
#define T_IN 8
#define FEAT 16
#define HID 128
#define H3 384
#define EE 320000
#define FUSER_IN 49
#define FUSER_H 96
#define GATE_H 48
#define ALPHA 0.5f

__device__ __forceinline__ float sigmoidf_(float v) { return 1.0f / (1.0f + expf(-v)); }

// ---------------- preprocessing ----------------

__global__ void init_kernel(int* first_eid, int* deg_cnt, int n) {
    int i = blockIdx.x * 256 + threadIdx.x;
    if (i < n) { first_eid[i] = 0x7fffffff; deg_cnt[i] = 0; }
}

__global__ void edge_pass1(const int* __restrict__ src, const int* __restrict__ dst,
                           int* first_eid, int* deg_cnt, int e) {
    int i = blockIdx.x * 256 + threadIdx.x;
    if (i < e) {
        atomicMin(&first_eid[src[i]], i);
        atomicAdd(&deg_cnt[dst[i]], 1);
    }
}

// single-block inclusive scan: row_ptr[i+1] = sum cnt[0..i]; fill_ptr[i] = row_ptr[i]
// also deg-derived quantities
__global__ __launch_bounds__(1024)
void scan_kernel(const int* __restrict__ cnt, int* row_ptr, int* fill_ptr,
                 float* dis, float* norm_self, int n) {
    __shared__ int buf[1024];
    __shared__ int s_carry;
    int tid = threadIdx.x;
    if (tid == 0) { s_carry = 0; row_ptr[0] = 0; }
    __syncthreads();
    for (int base = 0; base < n; base += 1024) {
        int i = base + tid;
        int v = (i < n) ? cnt[i] : 0;
        buf[tid] = v;
        __syncthreads();
        for (int off = 1; off < 1024; off <<= 1) {
            int t = (tid >= off) ? buf[tid - off] : 0;
            __syncthreads();
            buf[tid] += t;
            __syncthreads();
        }
        int incl = s_carry + buf[tid];
        if (i < n) {
            row_ptr[i + 1] = incl;
            fill_ptr[i] = incl - v;           // exclusive prefix
            float deg = (float)v + 1.0f;      // in-degree + self loop
            dis[i] = 1.0f / sqrtf(deg);
            norm_self[i] = 1.0f / deg;
        }
        __syncthreads();
        if (tid == 1023) s_carry += buf[1023];
        __syncthreads();
    }
}

__global__ void firsts_kernel(const int* __restrict__ first_eid, const int* __restrict__ dst,
                              const float* __restrict__ edge_attr,
                              int* first_out, float* first_dx, int n, int e) {
    int i = blockIdx.x * 256 + threadIdx.x;
    if (i >= n) return;
    int fe = first_eid[i];
    if (fe < e) {
        first_out[i] = dst[fe];
        first_dx[i] = fmaxf(edge_attr[fe], 1e-6f);
    } else {
        first_out[i] = -1;
        first_dx[i] = -1.0f;
    }
}

__global__ void edge_pass2(const int* __restrict__ src, const int* __restrict__ dst,
                           int* fill_ptr, const float* __restrict__ dis,
                           int* csr_src, float* csr_w, int e) {
    int i = blockIdx.x * 256 + threadIdx.x;
    if (i < e) {
        int d = dst[i], s = src[i];
        int pos = atomicAdd(&fill_ptr[d], 1);
        csr_src[pos] = s;
        csr_w[pos] = dis[s] * dis[d];
    }
}

__global__ void ghost_kernel(const int* __restrict__ mask, const int* __restrict__ first_out,
                             const float* __restrict__ first_dx,
                             int* d1_of, int* d2_of, float* dxb_of, int n) {
    int i = blockIdx.x * 256 + threadIdx.x;
    if (i >= n || mask[i] != 0) return;
    int b = first_out[i];
    float dxb = fmaxf(first_dx[i], 1e-6f);
    int d1, d2;
    if (b < 0) { d1 = i; d2 = i; }  // not reachable with given setup
    else {
        int n1 = first_out[b]; d1 = (n1 < 0) ? b : n1;
        int n2 = first_out[d1]; d2 = (n2 < 0) ? d1 : n2;
    }
    d1_of[i] = d1; d2_of[i] = d2; dxb_of[i] = dxb;
}

__global__ void zero_kernel(float* p, int n) {
    int i = blockIdx.x * 256 + threadIdx.x;
    if (i < n) p[i] = 0.0f;
}

// ---------------- per-step kernels ----------------

// One block (128 threads) per node: ghost fusion (if ghost) + g = relu(x_fused @ W_lin + b_lin)
__global__ __launch_bounds__(128)
void fuse_lin_kernel(const float* __restrict__ x, const int* __restrict__ mask,
                     const int* __restrict__ d1_of, const int* __restrict__ d2_of,
                     const float* __restrict__ dxb_of,
                     const float* __restrict__ Wf1, const float* __restrict__ bf1,
                     const float* __restrict__ Wf2, const float* __restrict__ bf2,
                     const float* __restrict__ Wg1, const float* __restrict__ bg1,
                     const float* __restrict__ Wg2, const float* __restrict__ bg2,
                     const float* __restrict__ W_lin, const float* __restrict__ b_lin,
                     float* __restrict__ g, int t) {
    int i = blockIdx.x;
    int j = threadIdx.x;
    __shared__ float feats[FUSER_IN];
    __shared__ float xf[FEAT];
    __shared__ float z1[FUSER_H];
    __shared__ float zg[GATE_H];
    __shared__ float s_gate;

    const float* xrow = &x[(i * T_IN + t) * FEAT];
    if (j < FEAT) { float v = xrow[j]; feats[j] = v; xf[j] = v; }

    bool ghost = (mask[i] == 0);
    if (ghost) {
        if (j < FEAT) {
            int d1 = d1_of[i], d2 = d2_of[i];
            feats[FEAT + j]     = x[(d1 * T_IN + t) * FEAT + j];
            feats[2 * FEAT + j] = x[(d2 * T_IN + t) * FEAT + j];
        }
        if (j == 0) feats[3 * FEAT] = dxb_of[i];
        __syncthreads();
        if (j < FUSER_H) {
            float acc = bf1[j];
            for (int k = 0; k < FUSER_IN; ++k) acc = fmaf(feats[k], Wf1[k * FUSER_H + j], acc);
            z1[j] = fmaxf(acc, 0.0f);
        }
        if (j < GATE_H) {
            float acc = bg1[j];
            for (int k = 0; k < FUSER_IN; ++k) acc = fmaf(feats[k], Wg1[k * GATE_H + j], acc);
            zg[j] = fmaxf(acc, 0.0f);
        }
        __syncthreads();
        if (j == 0) {
            float s = bg2[0];
            for (int k = 0; k < GATE_H; ++k) s = fmaf(zg[k], Wg2[k], s);
            s_gate = sigmoidf_(s);
        }
        __syncthreads();
        if (j < FEAT) {
            float acc = bf2[j];
            for (int k = 0; k < FUSER_H; ++k) acc = fmaf(z1[k], Wf2[k * FEAT + j], acc);
            xf[j] = feats[j] + ALPHA * acc * s_gate;
        }
    }
    __syncthreads();
    // linear: 16 -> 128, one output channel per thread
    float acc = b_lin[j];
    #pragma unroll
    for (int k = 0; k < FEAT; ++k) acc = fmaf(xf[k], W_lin[k * HID + j], acc);
    g[i * HID + j] = fmaxf(acc, 0.0f);
}

// C[M x Ncols] = A[M x 128] @ W[128 x Ncols], fp32, BM=64 BN=128 BK=16, 8x4 thread tile
__global__ __launch_bounds__(256)
void gemm_f32(const float* __restrict__ A, const float* __restrict__ W,
              float* __restrict__ C, int M, int Ncols) {
    __shared__ float As[16][68];   // transposed A tile, padded (272B rows, 16B aligned)
    __shared__ float Bs[16][128];
    const int row0 = blockIdx.x * 64;
    const int col0 = blockIdx.y * 128;
    const int tid = threadIdx.x;
    const int rg = tid >> 5;   // 0..7  (8 row groups of 8)
    const int cg = tid & 31;   // 0..31 (32 col groups of 4)
    float acc[8][4] = {};

    for (int k0 = 0; k0 < 128; k0 += 16) {
        {   // A tile: thread loads float4 of one row
            int r = tid >> 2;
            int kq = (tid & 3) << 2;
            float4 v = make_float4(0.f, 0.f, 0.f, 0.f);
            if (row0 + r < M)
                v = *reinterpret_cast<const float4*>(&A[(size_t)(row0 + r) * 128 + k0 + kq]);
            As[kq + 0][r] = v.x; As[kq + 1][r] = v.y; As[kq + 2][r] = v.z; As[kq + 3][r] = v.w;
        }
        {   // B tile: 16 x 128, two float4 per thread
            int c4 = (tid & 31) << 2;
            int kr = tid >> 5;
            *reinterpret_cast<float4*>(&Bs[kr][c4]) =
                *reinterpret_cast<const float4*>(&W[(size_t)(k0 + kr) * Ncols + col0 + c4]);
            *reinterpret_cast<float4*>(&Bs[kr + 8][c4]) =
                *reinterpret_cast<const float4*>(&W[(size_t)(k0 + kr + 8) * Ncols + col0 + c4]);
        }
        __syncthreads();
        #pragma unroll
        for (int k = 0; k < 16; ++k) {
            float4 a0 = *reinterpret_cast<const float4*>(&As[k][rg * 8]);
            float4 a1 = *reinterpret_cast<const float4*>(&As[k][rg * 8 + 4]);
            float4 bv = *reinterpret_cast<const float4*>(&Bs[k][cg * 4]);
            float a[8] = {a0.x, a0.y, a0.z, a0.w, a1.x, a1.y, a1.z, a1.w};
            float b[4] = {bv.x, bv.y, bv.z, bv.w};
            #pragma unroll
            for (int i2 = 0; i2 < 8; ++i2)
                #pragma unroll
                for (int j2 = 0; j2 < 4; ++j2)
                    acc[i2][j2] = fmaf(a[i2], b[j2], acc[i2][j2]);
        }
        __syncthreads();
    }
    #pragma unroll
    for (int i2 = 0; i2 < 8; ++i2) {
        int r = row0 + rg * 8 + i2;
        if (r < M) {
            float4 v = make_float4(acc[i2][0], acc[i2][1], acc[i2][2], acc[i2][3]);
            *reinterpret_cast<float4*>(&C[(size_t)r * Ncols + col0 + cg * 4]) = v;
        }
    }
}

// out[n][j] = relu( sum_in_edges hw[src]*w + hw[n]*norm_self + bias ), 2 nodes / 256-thread block
__global__ __launch_bounds__(256)
void gcn_agg(const float* __restrict__ hw, const int* __restrict__ row_ptr,
             const int* __restrict__ csr_src, const float* __restrict__ csr_w,
             const float* __restrict__ norm_self, const float* __restrict__ bias,
             float* __restrict__ out, int n) {
    int node = blockIdx.x * 2 + (threadIdx.x >> 7);
    int j = threadIdx.x & 127;
    if (node >= n) return;
    float acc = hw[(size_t)node * HID + j] * norm_self[node];
    int p0 = row_ptr[node], p1 = row_ptr[node + 1];
    for (int p = p0; p < p1; ++p) {
        int s = csr_src[p];
        float w = csr_w[p];
        acc = fmaf(hw[(size_t)s * HID + j], w, acc);
    }
    out[(size_t)node * HID + j] = fmaxf(acc + bias[j], 0.0f);
}

__global__ __launch_bounds__(256)
void gru_kernel(const float* __restrict__ gi, const float* __restrict__ gh,
                const float* __restrict__ b_ih, const float* __restrict__ b_hh,
                float* __restrict__ h, int n) {
    int idx = blockIdx.x * 256 + threadIdx.x;
    if (idx >= n * HID) return;
    int row = idx >> 7, j = idx & 127;
    const float* gir = gi + (size_t)row * H3;
    const float* ghr = gh + (size_t)row * H3;
    float ir = gir[j]           + b_ih[j];
    float iz = gir[HID + j]     + b_ih[HID + j];
    float in_ = gir[2 * HID + j] + b_ih[2 * HID + j];
    float hr = ghr[j]           + b_hh[j];
    float hz = ghr[HID + j]     + b_hh[HID + j];
    float hn = ghr[2 * HID + j] + b_hh[2 * HID + j];
    float r = sigmoidf_(ir + hr);
    float z = sigmoidf_(iz + hz);
    float nn = tanhf(in_ + r * hn);
    float hv = h[idx];
    h[idx] = (1.0f - z) * nn + z * hv;
}

// ---------------- launcher ----------------

extern "C" void kernel_launch(void* const* d_in, const int* in_sizes, int n_in,
                              void* d_out, int out_size, void* d_ws, size_t ws_size,
                              hipStream_t stream) {
    const float* x        = (const float*)d_in[0];
    const float* edge_attr= (const float*)d_in[1];
    const float* W_lin    = (const float*)d_in[2];
    const float* b_lin    = (const float*)d_in[3];
    const float* Wc1      = (const float*)d_in[4];
    const float* bc1      = (const float*)d_in[5];
    const float* Wc2      = (const float*)d_in[6];
    const float* bc2      = (const float*)d_in[7];
    const float* W_ih     = (const float*)d_in[8];
    const float* b_ih     = (const float*)d_in[9];
    const float* W_hh     = (const float*)d_in[10];
    const float* b_hh     = (const float*)d_in[11];
    const float* Wf1      = (const float*)d_in[12];
    const float* bf1      = (const float*)d_in[13];
    const float* Wf2      = (const float*)d_in[14];
    const float* bf2      = (const float*)d_in[15];
    const float* Wg1      = (const float*)d_in[16];
    const float* bg1      = (const float*)d_in[17];
    const float* Wg2      = (const float*)d_in[18];
    const float* bg2      = (const float*)d_in[19];
    const int*   edge_index = (const int*)d_in[20];
    const int*   mask     = (const int*)d_in[21];

    const int n = in_sizes[21];       // 20000
    const int e = in_sizes[1];        // 320000
    const int* src = edge_index;
    const int* dst = edge_index + e;
    float* h = (float*)d_out;         // [n,128], doubles as GRU state

    // workspace carve-up (256B aligned)
    char* w = (char*)d_ws;
    auto alloc = [&](size_t bytes) -> char* {
        char* p = w;
        w += (bytes + 255) & ~(size_t)255;
        return p;
    };
    int*   first_eid = (int*)  alloc((size_t)n * 4);
    int*   deg_cnt   = (int*)  alloc((size_t)n * 4);
    int*   row_ptr   = (int*)  alloc((size_t)(n + 1) * 4);
    int*   fill_ptr  = (int*)  alloc((size_t)n * 4);
    float* dis       = (float*)alloc((size_t)n * 4);
    float* norm_self = (float*)alloc((size_t)n * 4);
    int*   first_out = (int*)  alloc((size_t)n * 4);
    float* first_dx  = (float*)alloc((size_t)n * 4);
    int*   d1_of     = (int*)  alloc((size_t)n * 4);
    int*   d2_of     = (int*)  alloc((size_t)n * 4);
    float* dxb_of    = (float*)alloc((size_t)n * 4);
    int*   csr_src   = (int*)  alloc((size_t)e * 4);
    float* csr_w     = (float*)alloc((size_t)e * 4);
    float* bufG      = (float*)alloc((size_t)n * HID * 4);
    float* bufH      = (float*)alloc((size_t)n * HID * 4);
    float* bufGi     = (float*)alloc((size_t)n * H3 * 4);
    float* bufGh     = (float*)alloc((size_t)n * H3 * 4);

    const int TPB = 256;
    dim3 gN((n + TPB - 1) / TPB), gE((e + TPB - 1) / TPB);

    // preprocessing (time-invariant)
    init_kernel<<<gN, TPB, 0, stream>>>(first_eid, deg_cnt, n);
    edge_pass1<<<gE, TPB, 0, stream>>>(src, dst, first_eid, deg_cnt, e);
    scan_kernel<<<1, 1024, 0, stream>>>(deg_cnt, row_ptr, fill_ptr, dis, norm_self, n);
    firsts_kernel<<<gN, TPB, 0, stream>>>(first_eid, dst, edge_attr, first_out, first_dx, n, e);
    edge_pass2<<<gE, TPB, 0, stream>>>(src, dst, fill_ptr, dis, csr_src, csr_w, e);
    ghost_kernel<<<gN, TPB, 0, stream>>>(mask, first_out, first_dx, d1_of, d2_of, dxb_of, n);

    // h0 = 0
    zero_kernel<<<(n * HID + TPB - 1) / TPB, TPB, 0, stream>>>(h, n * HID);

    dim3 gemm_grid128((n + 63) / 64, 1);
    dim3 gemm_grid384((n + 63) / 64, 3);
    dim3 agg_grid((n + 1) / 2);

    for (int t = 0; t < T_IN; ++t) {
        // ghost fusion + input linear -> bufG
        fuse_lin_kernel<<<n, 128, 0, stream>>>(x, mask, d1_of, d2_of, dxb_of,
                                               Wf1, bf1, Wf2, bf2, Wg1, bg1, Wg2, bg2,
                                               W_lin, b_lin, bufG, t);
        // GCN layer 1
        gemm_f32<<<gemm_grid128, 256, 0, stream>>>(bufG, Wc1, bufH, n, HID);
        gcn_agg<<<agg_grid, 256, 0, stream>>>(bufH, row_ptr, csr_src, csr_w, norm_self, bc1, bufG, n);
        // GCN layer 2
        gemm_f32<<<gemm_grid128, 256, 0, stream>>>(bufG, Wc2, bufH, n, HID);
        gcn_agg<<<agg_grid, 256, 0, stream>>>(bufH, row_ptr, csr_src, csr_w, norm_self, bc2, bufG, n);
        // GRU
        gemm_f32<<<gemm_grid384, 256, 0, stream>>>(bufG, W_ih, bufGi, n, H3);
        gemm_f32<<<gemm_grid384, 256, 0, stream>>>(h,    W_hh, bufGh, n, H3);
        gru_kernel<<<(n * HID + TPB - 1) / TPB, TPB, 0, stream>>>(bufGi, bufGh, b_ih, b_hh, h, n);
    }
}

// Round 2
// 1521.981 us; speedup vs baseline: 1.3982x; 1.3982x over previous
//
#include <hip/hip_runtime.h>
#include <math.h>

// Problem constants (match reference)
#define NN 20000
#define T_IN 8
#define FEAT 16
#define HID 128
#define H3 384
#define FUSER_IN 49
#define FUSER_H 96
#define GATE_H 48
#define ALPHA 0.5f

__device__ __forceinline__ float sigmoidf_(float v) { return 1.0f / (1.0f + expf(-v)); }

// ---------------- preprocessing ----------------

__global__ void init_kernel(int* first_eid, int* deg_cnt, int n) {
    int i = blockIdx.x * 256 + threadIdx.x;
    if (i < n) { first_eid[i] = 0x7fffffff; deg_cnt[i] = 0; }
}

__global__ void edge_pass1(const int* __restrict__ src, const int* __restrict__ dst,
                           int* first_eid, int* deg_cnt, int e) {
    int i = blockIdx.x * 256 + threadIdx.x;
    if (i < e) {
        atomicMin(&first_eid[src[i]], i);
        atomicAdd(&deg_cnt[dst[i]], 1);
    }
}

// single-block inclusive scan: row_ptr[i+1] = sum cnt[0..i]; fill_ptr[i] = exclusive
__global__ __launch_bounds__(1024)
void scan_kernel(const int* __restrict__ cnt, int* row_ptr, int* fill_ptr,
                 float* dis, float* norm_self, int n) {
    __shared__ int buf[1024];
    __shared__ int s_carry;
    int tid = threadIdx.x;
    if (tid == 0) { s_carry = 0; row_ptr[0] = 0; }
    __syncthreads();
    for (int base = 0; base < n; base += 1024) {
        int i = base + tid;
        int v = (i < n) ? cnt[i] : 0;
        buf[tid] = v;
        __syncthreads();
        for (int off = 1; off < 1024; off <<= 1) {
            int t = (tid >= off) ? buf[tid - off] : 0;
            __syncthreads();
            buf[tid] += t;
            __syncthreads();
        }
        int incl = s_carry + buf[tid];
        if (i < n) {
            row_ptr[i + 1] = incl;
            fill_ptr[i] = incl - v;           // exclusive prefix
            float deg = (float)v + 1.0f;      // in-degree + self loop
            dis[i] = 1.0f / sqrtf(deg);
            norm_self[i] = 1.0f / deg;
        }
        __syncthreads();
        if (tid == 1023) s_carry += buf[1023];
        __syncthreads();
    }
}

__global__ void firsts_kernel(const int* __restrict__ first_eid, const int* __restrict__ dst,
                              const float* __restrict__ edge_attr,
                              int* first_out, float* first_dx, int n, int e) {
    int i = blockIdx.x * 256 + threadIdx.x;
    if (i >= n) return;
    int fe = first_eid[i];
    if (fe < e) {
        first_out[i] = dst[fe];
        first_dx[i] = fmaxf(edge_attr[fe], 1e-6f);
    } else {
        first_out[i] = -1;
        first_dx[i] = -1.0f;
    }
}

__global__ void edge_pass2(const int* __restrict__ src, const int* __restrict__ dst,
                           int* fill_ptr, const float* __restrict__ dis,
                           int* csr_src, float* csr_w, int e) {
    int i = blockIdx.x * 256 + threadIdx.x;
    if (i < e) {
        int d = dst[i], s = src[i];
        int pos = atomicAdd(&fill_ptr[d], 1);
        csr_src[pos] = s;
        csr_w[pos] = dis[s] * dis[d];
    }
}

__global__ void ghost_kernel(const int* __restrict__ mask, const int* __restrict__ first_out,
                             const float* __restrict__ first_dx,
                             int* d1_of, int* d2_of, float* dxb_of, int n) {
    int i = blockIdx.x * 256 + threadIdx.x;
    if (i >= n || mask[i] != 0) return;
    int b = first_out[i];
    float dxb = fmaxf(first_dx[i], 1e-6f);
    int d1, d2;
    if (b < 0) { d1 = i; d2 = i; }
    else {
        int n1 = first_out[b]; d1 = (n1 < 0) ? b : n1;
        int n2 = first_out[d1]; d2 = (n2 < 0) ? d1 : n2;
    }
    d1_of[i] = d1; d2_of[i] = d2; dxb_of[i] = dxb;
}

__global__ void zero_kernel(float* p, int n) {
    int i = blockIdx.x * 256 + threadIdx.x;
    if (i < n) p[i] = 0.0f;
}

// ---------------- per-step kernels ----------------

// One block (128 threads) per node: ghost fusion (if ghost) + g = relu(x_fused @ W_lin + b_lin)
__global__ __launch_bounds__(128)
void fuse_lin_kernel(const float* __restrict__ x, const int* __restrict__ mask,
                     const int* __restrict__ d1_of, const int* __restrict__ d2_of,
                     const float* __restrict__ dxb_of,
                     const float* __restrict__ Wf1, const float* __restrict__ bf1,
                     const float* __restrict__ Wf2, const float* __restrict__ bf2,
                     const float* __restrict__ Wg1, const float* __restrict__ bg1,
                     const float* __restrict__ Wg2, const float* __restrict__ bg2,
                     const float* __restrict__ W_lin, const float* __restrict__ b_lin,
                     float* __restrict__ g, int t) {
    int i = blockIdx.x;
    int j = threadIdx.x;
    __shared__ float feats[FUSER_IN];
    __shared__ float xf[FEAT];
    __shared__ float z1[FUSER_H];
    __shared__ float zg[GATE_H];
    __shared__ float s_gate;

    const float* xrow = &x[(i * T_IN + t) * FEAT];
    if (j < FEAT) { float v = xrow[j]; feats[j] = v; xf[j] = v; }

    bool ghost = (mask[i] == 0);
    if (ghost) {
        if (j < FEAT) {
            int d1 = d1_of[i], d2 = d2_of[i];
            feats[FEAT + j]     = x[(d1 * T_IN + t) * FEAT + j];
            feats[2 * FEAT + j] = x[(d2 * T_IN + t) * FEAT + j];
        }
        if (j == 0) feats[3 * FEAT] = dxb_of[i];
        __syncthreads();
        if (j < FUSER_H) {
            float acc = bf1[j];
            for (int k = 0; k < FUSER_IN; ++k) acc = fmaf(feats[k], Wf1[k * FUSER_H + j], acc);
            z1[j] = fmaxf(acc, 0.0f);
        }
        if (j < GATE_H) {
            float acc = bg1[j];
            for (int k = 0; k < FUSER_IN; ++k) acc = fmaf(feats[k], Wg1[k * GATE_H + j], acc);
            zg[j] = fmaxf(acc, 0.0f);
        }
        __syncthreads();
        if (j == 0) {
            float s = bg2[0];
            for (int k = 0; k < GATE_H; ++k) s = fmaf(zg[k], Wg2[k], s);
            s_gate = sigmoidf_(s);
        }
        __syncthreads();
        if (j < FEAT) {
            float acc = bf2[j];
            for (int k = 0; k < FUSER_H; ++k) acc = fmaf(z1[k], Wf2[k * FEAT + j], acc);
            xf[j] = feats[j] + ALPHA * acc * s_gate;
        }
    }
    __syncthreads();
    float acc = b_lin[j];
    #pragma unroll
    for (int k = 0; k < FEAT; ++k) acc = fmaf(xf[k], W_lin[k * HID + j], acc);
    g[i * HID + j] = fmaxf(acc, 0.0f);
}

// C = A[M x 128] @ B[128 x Ncols]. BM=128 BN=128 BK=16, 8x8 per thread (split 4+4).
// blockIdx.z selects (A1,B1,C1) or (A2,B2,C2) so two GEMMs go in one dispatch.
__global__ __launch_bounds__(256)
void gemm_f32(const float* __restrict__ A1, const float* __restrict__ B1, float* __restrict__ C1,
              const float* __restrict__ A2, const float* __restrict__ B2, float* __restrict__ C2,
              int M, int Ncols) {
    __shared__ float As[16][132];   // k-major, padded
    __shared__ float Bs[16][128];
    const float* A = blockIdx.z ? A2 : A1;
    const float* B = blockIdx.z ? B2 : B1;
    float*       C = blockIdx.z ? C2 : C1;
    const int row0 = blockIdx.x * 128;
    const int col0 = blockIdx.y * 128;
    const int tid = threadIdx.x;
    const int rg = tid >> 4;        // 0..15 -> rows rg*4 and 64+rg*4
    const int cg = tid & 15;        // 0..15 -> cols cg*4 and 64+cg*4
    const int ar  = tid >> 1;       // 0..127 (A stage row)
    const int akq = (tid & 1) * 8;  // 0 or 8 (A stage k base)
    const int bkr = tid >> 5;       // 0..7
    const int bc4 = (tid & 31) * 4; // 0..124
    float acc[8][8] = {};

    for (int k0 = 0; k0 < 128; k0 += 16) {
        {   // A tile (transpose into As[k][m]), zero-fill OOB rows
            float4 v0 = make_float4(0.f,0.f,0.f,0.f), v1 = v0;
            int r = row0 + ar;
            if (r < M) {
                const float* ap = &A[(size_t)r * 128 + k0 + akq];
                v0 = *reinterpret_cast<const float4*>(ap);
                v1 = *reinterpret_cast<const float4*>(ap + 4);
            }
            As[akq + 0][ar] = v0.x; As[akq + 1][ar] = v0.y;
            As[akq + 2][ar] = v0.z; As[akq + 3][ar] = v0.w;
            As[akq + 4][ar] = v1.x; As[akq + 5][ar] = v1.y;
            As[akq + 6][ar] = v1.z; As[akq + 7][ar] = v1.w;
        }
        {   // B tile: 16 x 128
            const float* bp = &B[(size_t)(k0 + bkr) * Ncols + col0 + bc4];
            *reinterpret_cast<float4*>(&Bs[bkr][bc4]) = *reinterpret_cast<const float4*>(bp);
            *reinterpret_cast<float4*>(&Bs[bkr + 8][bc4]) =
                *reinterpret_cast<const float4*>(bp + (size_t)8 * Ncols);
        }
        __syncthreads();
        #pragma unroll
        for (int k = 0; k < 16; ++k) {
            float4 alo = *reinterpret_cast<const float4*>(&As[k][rg * 4]);
            float4 ahi = *reinterpret_cast<const float4*>(&As[k][64 + rg * 4]);
            float4 blo = *reinterpret_cast<const float4*>(&Bs[k][cg * 4]);
            float4 bhi = *reinterpret_cast<const float4*>(&Bs[k][64 + cg * 4]);
            float av[8] = {alo.x, alo.y, alo.z, alo.w, ahi.x, ahi.y, ahi.z, ahi.w};
            float bv[8] = {blo.x, blo.y, blo.z, blo.w, bhi.x, bhi.y, bhi.z, bhi.w};
            #pragma unroll
            for (int i2 = 0; i2 < 8; ++i2)
                #pragma unroll
                for (int j2 = 0; j2 < 8; ++j2)
                    acc[i2][j2] = fmaf(av[i2], bv[j2], acc[i2][j2]);
        }
        __syncthreads();
    }
    #pragma unroll
    for (int i2 = 0; i2 < 8; ++i2) {
        int r = row0 + ((i2 < 4) ? (rg * 4 + i2) : (64 + rg * 4 + (i2 - 4)));
        if (r < M) {
            float4 lo = make_float4(acc[i2][0], acc[i2][1], acc[i2][2], acc[i2][3]);
            float4 hi = make_float4(acc[i2][4], acc[i2][5], acc[i2][6], acc[i2][7]);
            *reinterpret_cast<float4*>(&C[(size_t)r * Ncols + col0 + cg * 4]) = lo;
            *reinterpret_cast<float4*>(&C[(size_t)r * Ncols + col0 + 64 + cg * 4]) = hi;
        }
    }
}

// out[node][:] = relu(sum_in hw[src]*w + hw[node]*norm_self + bias)
// 32 threads per node (float4 per lane), 8 nodes per 256-thread block, edge loop unrolled x4
__global__ __launch_bounds__(256)
void gcn_agg(const float* __restrict__ hw, const int* __restrict__ row_ptr,
             const int* __restrict__ csr_src, const float* __restrict__ csr_w,
             const float* __restrict__ norm_self, const float* __restrict__ bias,
             float* __restrict__ out, int n) {
    int node = blockIdx.x * 8 + (threadIdx.x >> 5);
    int lane = threadIdx.x & 31;
    if (node >= n) return;
    const float4* hw4 = reinterpret_cast<const float4*>(hw);
    float4 self = hw4[(size_t)node * 32 + lane];
    float ns = norm_self[node];
    float4 a0, a1, a2, a3;
    a0.x = self.x * ns; a0.y = self.y * ns; a0.z = self.z * ns; a0.w = self.w * ns;
    a1 = make_float4(0.f,0.f,0.f,0.f); a2 = a1; a3 = a1;
    int p  = row_ptr[node];
    int p1 = row_ptr[node + 1];
    for (; p + 4 <= p1; p += 4) {
        int s0 = csr_src[p], s1 = csr_src[p+1], s2 = csr_src[p+2], s3 = csr_src[p+3];
        float w0 = csr_w[p], w1 = csr_w[p+1], w2 = csr_w[p+2], w3 = csr_w[p+3];
        float4 v0 = hw4[(size_t)s0 * 32 + lane];
        float4 v1 = hw4[(size_t)s1 * 32 + lane];
        float4 v2 = hw4[(size_t)s2 * 32 + lane];
        float4 v3 = hw4[(size_t)s3 * 32 + lane];
        a0.x = fmaf(v0.x, w0, a0.x); a0.y = fmaf(v0.y, w0, a0.y);
        a0.z = fmaf(v0.z, w0, a0.z); a0.w = fmaf(v0.w, w0, a0.w);
        a1.x = fmaf(v1.x, w1, a1.x); a1.y = fmaf(v1.y, w1, a1.y);
        a1.z = fmaf(v1.z, w1, a1.z); a1.w = fmaf(v1.w, w1, a1.w);
        a2.x = fmaf(v2.x, w2, a2.x); a2.y = fmaf(v2.y, w2, a2.y);
        a2.z = fmaf(v2.z, w2, a2.z); a2.w = fmaf(v2.w, w2, a2.w);
        a3.x = fmaf(v3.x, w3, a3.x); a3.y = fmaf(v3.y, w3, a3.y);
        a3.z = fmaf(v3.z, w3, a3.z); a3.w = fmaf(v3.w, w3, a3.w);
    }
    for (; p < p1; ++p) {
        int s = csr_src[p];
        float w = csr_w[p];
        float4 v = hw4[(size_t)s * 32 + lane];
        a0.x = fmaf(v.x, w, a0.x); a0.y = fmaf(v.y, w, a0.y);
        a0.z = fmaf(v.z, w, a0.z); a0.w = fmaf(v.w, w, a0.w);
    }
    float4 b4 = reinterpret_cast<const float4*>(bias)[lane];
    float4 o;
    o.x = fmaxf(a0.x + a1.x + a2.x + a3.x + b4.x, 0.0f);
    o.y = fmaxf(a0.y + a1.y + a2.y + a3.y + b4.y, 0.0f);
    o.z = fmaxf(a0.z + a1.z + a2.z + a3.z + b4.z, 0.0f);
    o.w = fmaxf(a0.w + a1.w + a2.w + a3.w + b4.w, 0.0f);
    reinterpret_cast<float4*>(out)[(size_t)node * 32 + lane] = o;
}

__global__ __launch_bounds__(256)
void gru_kernel(const float* __restrict__ gi, const float* __restrict__ gh,
                const float* __restrict__ b_ih, const float* __restrict__ b_hh,
                float* __restrict__ h, int n) {
    int idx = blockIdx.x * 256 + threadIdx.x;     // one float4 of h per thread
    if (idx >= n * 32) return;
    int row = idx >> 5, q = idx & 31;
    const float4* gi4 = reinterpret_cast<const float4*>(gi + (size_t)row * H3);
    const float4* gh4 = reinterpret_cast<const float4*>(gh + (size_t)row * H3);
    const float4* bi4 = reinterpret_cast<const float4*>(b_ih);
    const float4* bh4 = reinterpret_cast<const float4*>(b_hh);
    float4 vir = gi4[q], viz = gi4[32 + q], vin = gi4[64 + q];
    float4 vhr = gh4[q], vhz = gh4[32 + q], vhn = gh4[64 + q];
    float4 bir = bi4[q], biz = bi4[32 + q], bin_ = bi4[64 + q];
    float4 bhr = bh4[q], bhz = bh4[32 + q], bhn = bh4[64 + q];
    float4* h4 = reinterpret_cast<float4*>(h);
    float4 hv = h4[idx];
    float4 o;
    {
        float r = sigmoidf_((vir.x + bir.x) + (vhr.x + bhr.x));
        float z = sigmoidf_((viz.x + biz.x) + (vhz.x + bhz.x));
        float nn = tanhf((vin.x + bin_.x) + r * (vhn.x + bhn.x));
        o.x = (1.0f - z) * nn + z * hv.x;
    }
    {
        float r = sigmoidf_((vir.y + bir.y) + (vhr.y + bhr.y));
        float z = sigmoidf_((viz.y + biz.y) + (vhz.y + bhz.y));
        float nn = tanhf((vin.y + bin_.y) + r * (vhn.y + bhn.y));
        o.y = (1.0f - z) * nn + z * hv.y;
    }
    {
        float r = sigmoidf_((vir.z + bir.z) + (vhr.z + bhr.z));
        float z = sigmoidf_((viz.z + biz.z) + (vhz.z + bhz.z));
        float nn = tanhf((vin.z + bin_.z) + r * (vhn.z + bhn.z));
        o.z = (1.0f - z) * nn + z * hv.z;
    }
    {
        float r = sigmoidf_((vir.w + bir.w) + (vhr.w + bhr.w));
        float z = sigmoidf_((viz.w + biz.w) + (vhz.w + bhz.w));
        float nn = tanhf((vin.w + bin_.w) + r * (vhn.w + bhn.w));
        o.w = (1.0f - z) * nn + z * hv.w;
    }
    h4[idx] = o;
}

// ---------------- launcher ----------------

extern "C" void kernel_launch(void* const* d_in, const int* in_sizes, int n_in,
                              void* d_out, int out_size, void* d_ws, size_t ws_size,
                              hipStream_t stream) {
    const float* x        = (const float*)d_in[0];
    const float* edge_attr= (const float*)d_in[1];
    const float* W_lin    = (const float*)d_in[2];
    const float* b_lin    = (const float*)d_in[3];
    const float* Wc1      = (const float*)d_in[4];
    const float* bc1      = (const float*)d_in[5];
    const float* Wc2      = (const float*)d_in[6];
    const float* bc2      = (const float*)d_in[7];
    const float* W_ih     = (const float*)d_in[8];
    const float* b_ih     = (const float*)d_in[9];
    const float* W_hh     = (const float*)d_in[10];
    const float* b_hh     = (const float*)d_in[11];
    const float* Wf1      = (const float*)d_in[12];
    const float* bf1      = (const float*)d_in[13];
    const float* Wf2      = (const float*)d_in[14];
    const float* bf2      = (const float*)d_in[15];
    const float* Wg1      = (const float*)d_in[16];
    const float* bg1      = (const float*)d_in[17];
    const float* Wg2      = (const float*)d_in[18];
    const float* bg2      = (const float*)d_in[19];
    const int*   edge_index = (const int*)d_in[20];
    const int*   mask     = (const int*)d_in[21];

    const int n = in_sizes[21];       // 20000
    const int e = in_sizes[1];        // 320000
    const int* src = edge_index;
    const int* dst = edge_index + e;
    float* h = (float*)d_out;         // [n,128], GRU state

    char* w = (char*)d_ws;
    auto alloc = [&](size_t bytes) -> char* {
        char* p = w;
        w += (bytes + 255) & ~(size_t)255;
        return p;
    };
    int*   first_eid = (int*)  alloc((size_t)n * 4);
    int*   deg_cnt   = (int*)  alloc((size_t)n * 4);
    int*   row_ptr   = (int*)  alloc((size_t)(n + 1) * 4);
    int*   fill_ptr  = (int*)  alloc((size_t)n * 4);
    float* dis       = (float*)alloc((size_t)n * 4);
    float* norm_self = (float*)alloc((size_t)n * 4);
    int*   first_out = (int*)  alloc((size_t)n * 4);
    float* first_dx  = (float*)alloc((size_t)n * 4);
    int*   d1_of     = (int*)  alloc((size_t)n * 4);
    int*   d2_of     = (int*)  alloc((size_t)n * 4);
    float* dxb_of    = (float*)alloc((size_t)n * 4);
    int*   csr_src   = (int*)  alloc((size_t)e * 4);
    float* csr_w     = (float*)alloc((size_t)e * 4);
    float* bufG      = (float*)alloc((size_t)n * HID * 4);
    float* bufH      = (float*)alloc((size_t)n * HID * 4);
    float* bufGi     = (float*)alloc((size_t)n * H3 * 4);
    float* bufGh     = (float*)alloc((size_t)n * H3 * 4);

    const int TPB = 256;
    dim3 gN((n + TPB - 1) / TPB), gE((e + TPB - 1) / TPB);

    // preprocessing (time-invariant)
    init_kernel<<<gN, TPB, 0, stream>>>(first_eid, deg_cnt, n);
    edge_pass1<<<gE, TPB, 0, stream>>>(src, dst, first_eid, deg_cnt, e);
    scan_kernel<<<1, 1024, 0, stream>>>(deg_cnt, row_ptr, fill_ptr, dis, norm_self, n);
    firsts_kernel<<<gN, TPB, 0, stream>>>(first_eid, dst, edge_attr, first_out, first_dx, n, e);
    edge_pass2<<<gE, TPB, 0, stream>>>(src, dst, fill_ptr, dis, csr_src, csr_w, e);
    ghost_kernel<<<gN, TPB, 0, stream>>>(mask, first_out, first_dx, d1_of, d2_of, dxb_of, n);

    zero_kernel<<<(n * HID + TPB - 1) / TPB, TPB, 0, stream>>>(h, n * HID);

    const int mblocks = (n + 127) / 128;
    dim3 grid_gcn(mblocks, 1, 1);       // 128-col GEMM, single
    dim3 grid_gru(mblocks, 3, 2);       // 384-col GEMM, gi and gh in one dispatch
    dim3 agg_grid((n + 7) / 8);

    for (int t = 0; t < T_IN; ++t) {
        fuse_lin_kernel<<<n, 128, 0, stream>>>(x, mask, d1_of, d2_of, dxb_of,
                                               Wf1, bf1, Wf2, bf2, Wg1, bg1, Wg2, bg2,
                                               W_lin, b_lin, bufG, t);
        // GCN layer 1
        gemm_f32<<<grid_gcn, 256, 0, stream>>>(bufG, Wc1, bufH, bufG, Wc1, bufH, n, HID);
        gcn_agg<<<agg_grid, 256, 0, stream>>>(bufH, row_ptr, csr_src, csr_w, norm_self, bc1, bufG, n);
        // GCN layer 2
        gemm_f32<<<grid_gcn, 256, 0, stream>>>(bufG, Wc2, bufH, bufG, Wc2, bufH, n, HID);
        gcn_agg<<<agg_grid, 256, 0, stream>>>(bufH, row_ptr, csr_src, csr_w, norm_self, bc2, bufG, n);
        // GRU: gi = g@W_ih, gh = h@W_hh in one dispatch (blockIdx.z)
        gemm_f32<<<grid_gru, 256, 0, stream>>>(bufG, W_ih, bufGi, h, W_hh, bufGh, n, H3);
        gru_kernel<<<(n * 32 + TPB - 1) / TPB, TPB, 0, stream>>>(bufGi, bufGh, b_ih, b_hh, h, n);
    }
}

// Round 3
// 1297.723 us; speedup vs baseline: 1.6399x; 1.1728x over previous
//
#include <hip/hip_runtime.h>
#include <math.h>

// Problem constants (match reference)
#define NN 20000
#define T_IN 8
#define FEAT 16
#define HID 128
#define H3 384
#define FUSER_IN 49
#define FUSER_H 96
#define GATE_H 48
#define ALPHA 0.5f

typedef unsigned short u16;
typedef __attribute__((ext_vector_type(8))) short bf16x8_t;
typedef __attribute__((ext_vector_type(4))) float f32x4_t;

__device__ __forceinline__ float sigmoidf_(float v) { return 1.0f / (1.0f + expf(-v)); }

// bf16 round-to-nearest-even (finite values only)
__device__ __forceinline__ u16 f2b(float v) {
    unsigned u = __float_as_uint(v);
    unsigned r = (u + 0x7fffu + ((u >> 16) & 1u)) >> 16;
    return (u16)r;
}
__device__ __forceinline__ float b2f(u16 u) { return __uint_as_float(((unsigned)u) << 16); }

// ---------------- preprocessing ----------------

__global__ void init_kernel(int* first_eid, int* deg_cnt, int n) {
    int i = blockIdx.x * 256 + threadIdx.x;
    if (i < n) { first_eid[i] = 0x7fffffff; deg_cnt[i] = 0; }
}

__global__ void edge_pass1(const int* __restrict__ src, const int* __restrict__ dst,
                           int* first_eid, int* deg_cnt, int e) {
    int i = blockIdx.x * 256 + threadIdx.x;
    if (i < e) {
        atomicMin(&first_eid[src[i]], i);
        atomicAdd(&deg_cnt[dst[i]], 1);
    }
}

__global__ __launch_bounds__(1024)
void scan_kernel(const int* __restrict__ cnt, int* row_ptr, int* fill_ptr,
                 float* dis, float* norm_self, int n) {
    __shared__ int buf[1024];
    __shared__ int s_carry;
    int tid = threadIdx.x;
    if (tid == 0) { s_carry = 0; row_ptr[0] = 0; }
    __syncthreads();
    for (int base = 0; base < n; base += 1024) {
        int i = base + tid;
        int v = (i < n) ? cnt[i] : 0;
        buf[tid] = v;
        __syncthreads();
        for (int off = 1; off < 1024; off <<= 1) {
            int t = (tid >= off) ? buf[tid - off] : 0;
            __syncthreads();
            buf[tid] += t;
            __syncthreads();
        }
        int incl = s_carry + buf[tid];
        if (i < n) {
            row_ptr[i + 1] = incl;
            fill_ptr[i] = incl - v;
            float deg = (float)v + 1.0f;
            dis[i] = 1.0f / sqrtf(deg);
            norm_self[i] = 1.0f / deg;
        }
        __syncthreads();
        if (tid == 1023) s_carry += buf[1023];
        __syncthreads();
    }
}

__global__ void firsts_kernel(const int* __restrict__ first_eid, const int* __restrict__ dst,
                              const float* __restrict__ edge_attr,
                              int* first_out, float* first_dx, int n, int e) {
    int i = blockIdx.x * 256 + threadIdx.x;
    if (i >= n) return;
    int fe = first_eid[i];
    if (fe < e) {
        first_out[i] = dst[fe];
        first_dx[i] = fmaxf(edge_attr[fe], 1e-6f);
    } else {
        first_out[i] = -1;
        first_dx[i] = -1.0f;
    }
}

__global__ void edge_pass2(const int* __restrict__ src, const int* __restrict__ dst,
                           int* fill_ptr, const float* __restrict__ dis,
                           int* csr_src, float* csr_w, int e) {
    int i = blockIdx.x * 256 + threadIdx.x;
    if (i < e) {
        int d = dst[i], s = src[i];
        int pos = atomicAdd(&fill_ptr[d], 1);
        csr_src[pos] = s;
        csr_w[pos] = dis[s] * dis[d];
    }
}

__global__ void ghost_kernel(const int* __restrict__ mask, const int* __restrict__ first_out,
                             const float* __restrict__ first_dx,
                             int* d1_of, int* d2_of, float* dxb_of, int n) {
    int i = blockIdx.x * 256 + threadIdx.x;
    if (i >= n || mask[i] != 0) return;
    int b = first_out[i];
    float dxb = fmaxf(first_dx[i], 1e-6f);
    int d1, d2;
    if (b < 0) { d1 = i; d2 = i; }
    else {
        int n1 = first_out[b]; d1 = (n1 < 0) ? b : n1;
        int n2 = first_out[d1]; d2 = (n2 < 0) ? d1 : n2;
    }
    d1_of[i] = d1; d2_of[i] = d2; dxb_of[i] = dxb;
}

__global__ void zero_kernel(float* p, int n) {
    int i = blockIdx.x * 256 + threadIdx.x;
    if (i < n) p[i] = 0.0f;
}

// W[k][nn] (K=128 rows) -> BT_hi/BT_lo[nn][k] bf16 split
__global__ void wsplit_kernel(const float* __restrict__ W, u16* BT_hi, u16* BT_lo, int Ncols) {
    int idx = blockIdx.x * 256 + threadIdx.x;
    if (idx >= Ncols * 128) return;
    int nn = idx >> 7, k = idx & 127;
    float v = W[(size_t)k * Ncols + nn];
    u16 h = f2b(v);
    BT_hi[idx] = h;
    BT_lo[idx] = f2b(v - b2f(h));
}

// ---------------- per-step kernels ----------------

// One block (128 threads) per node: ghost fusion (if ghost) + g = relu(x_fused @ W_lin + b_lin)
// Writes g as bf16 hi/lo split (consumed only by the MFMA GEMM).
__global__ __launch_bounds__(128)
void fuse_lin_kernel(const float* __restrict__ x, const int* __restrict__ mask,
                     const int* __restrict__ d1_of, const int* __restrict__ d2_of,
                     const float* __restrict__ dxb_of,
                     const float* __restrict__ Wf1, const float* __restrict__ bf1,
                     const float* __restrict__ Wf2, const float* __restrict__ bf2,
                     const float* __restrict__ Wg1, const float* __restrict__ bg1,
                     const float* __restrict__ Wg2, const float* __restrict__ bg2,
                     const float* __restrict__ W_lin, const float* __restrict__ b_lin,
                     u16* __restrict__ g_hi, u16* __restrict__ g_lo, int t) {
    int i = blockIdx.x;
    int j = threadIdx.x;
    __shared__ float feats[FUSER_IN];
    __shared__ float xf[FEAT];
    __shared__ float z1[FUSER_H];
    __shared__ float zg[GATE_H];
    __shared__ float s_gate;

    const float* xrow = &x[(i * T_IN + t) * FEAT];
    if (j < FEAT) { float v = xrow[j]; feats[j] = v; xf[j] = v; }

    bool ghost = (mask[i] == 0);
    if (ghost) {
        if (j < FEAT) {
            int d1 = d1_of[i], d2 = d2_of[i];
            feats[FEAT + j]     = x[(d1 * T_IN + t) * FEAT + j];
            feats[2 * FEAT + j] = x[(d2 * T_IN + t) * FEAT + j];
        }
        if (j == 0) feats[3 * FEAT] = dxb_of[i];
        __syncthreads();
        if (j < FUSER_H) {
            float acc = bf1[j];
            for (int k = 0; k < FUSER_IN; ++k) acc = fmaf(feats[k], Wf1[k * FUSER_H + j], acc);
            z1[j] = fmaxf(acc, 0.0f);
        }
        if (j < GATE_H) {
            float acc = bg1[j];
            for (int k = 0; k < FUSER_IN; ++k) acc = fmaf(feats[k], Wg1[k * GATE_H + j], acc);
            zg[j] = fmaxf(acc, 0.0f);
        }
        __syncthreads();
        if (j == 0) {
            float s = bg2[0];
            for (int k = 0; k < GATE_H; ++k) s = fmaf(zg[k], Wg2[k], s);
            s_gate = sigmoidf_(s);
        }
        __syncthreads();
        if (j < FEAT) {
            float acc = bf2[j];
            for (int k = 0; k < FUSER_H; ++k) acc = fmaf(z1[k], Wf2[k * FEAT + j], acc);
            xf[j] = feats[j] + ALPHA * acc * s_gate;
        }
    }
    __syncthreads();
    float acc = b_lin[j];
    #pragma unroll
    for (int k = 0; k < FEAT; ++k) acc = fmaf(xf[k], W_lin[k * HID + j], acc);
    float v = fmaxf(acc, 0.0f);
    u16 hv = f2b(v);
    g_hi[(size_t)i * HID + j] = hv;
    g_lo[(size_t)i * HID + j] = f2b(v - b2f(hv));
}

// C[M x Ncols] (fp32) = A[M x 128] @ B[128 x Ncols] via bf16x3 split MFMA.
// A given as hi/lo bf16 [M][128]; B as pre-transposed/split BT[n][128] bf16.
// Tile BM=128, BN=128, 4 waves (2x2), wave tile 64x64 = 4x4 frags of 16x16x32.
// K=128 staged fully in LDS (XOR-swizzled), one barrier per block.
// blockIdx.z picks operand set 1 or 2 (two GEMMs per dispatch).
__global__ __launch_bounds__(256)
void gemm_mfma(const u16* __restrict__ Ahi1, const u16* __restrict__ Alo1,
               const u16* __restrict__ BThi1, const u16* __restrict__ BTlo1,
               float* __restrict__ C1,
               const u16* __restrict__ Ahi2, const u16* __restrict__ Alo2,
               const u16* __restrict__ BThi2, const u16* __restrict__ BTlo2,
               float* __restrict__ C2,
               int M, int Ncols) {
    __shared__ u16 ldsA[2][128 * 128];   // [hi/lo][row*128+k], XOR-swizzled; 64 KB
    const u16* Ahi  = blockIdx.z ? Ahi2  : Ahi1;
    const u16* Alo  = blockIdx.z ? Alo2  : Alo1;
    const u16* BThi = blockIdx.z ? BThi2 : BThi1;
    const u16* BTlo = blockIdx.z ? BTlo2 : BTlo1;
    float*     C    = blockIdx.z ? C2    : C1;

    const int tid  = threadIdx.x;
    const int row0 = blockIdx.x * 128;
    const int col0 = blockIdx.y * 128;

    // stage A hi+lo: 8 units of 16B per thread per component
    #pragma unroll
    for (int it = 0; it < 8; ++it) {
        int unit = tid + it * 256;         // 0..2047
        int r = unit >> 4, s = unit & 15;  // row, 16B segment
        int gr = row0 + r;
        uint4 vh = make_uint4(0, 0, 0, 0), vl = vh;
        if (gr < M) {
            vh = *reinterpret_cast<const uint4*>(&Ahi[(size_t)gr * 128 + s * 8]);
            vl = *reinterpret_cast<const uint4*>(&Alo[(size_t)gr * 128 + s * 8]);
        }
        int byte = (r * 256 + s * 16) ^ ((r & 7) << 4);
        *reinterpret_cast<uint4*>((char*)(&ldsA[0][0]) + byte) = vh;
        *reinterpret_cast<uint4*>((char*)(&ldsA[1][0]) + byte) = vl;
    }
    __syncthreads();

    const int wid  = tid >> 6;
    const int lane = tid & 63;
    const int wr = (wid >> 1) * 64;    // wave row base within tile
    const int wc = (wid & 1) * 64;     // wave col base within tile
    const int l15 = lane & 15;
    const int lkh = lane >> 4;         // k-chunk 0..3

    f32x4_t acc[4][4] = {};

    #pragma unroll
    for (int kb = 0; kb < 4; ++kb) {
        bf16x8_t ah[4], al[4], bh[4], bl[4];
        #pragma unroll
        for (int m = 0; m < 4; ++m) {
            int row = wr + m * 16 + l15;
            int byte = (row * 256 + kb * 64 + lkh * 16) ^ ((row & 7) << 4);
            ah[m] = *reinterpret_cast<const bf16x8_t*>((const char*)(&ldsA[0][0]) + byte);
            al[m] = *reinterpret_cast<const bf16x8_t*>((const char*)(&ldsA[1][0]) + byte);
        }
        #pragma unroll
        for (int nf = 0; nf < 4; ++nf) {
            int col = col0 + wc + nf * 16 + l15;
            size_t off = (size_t)col * 128 + kb * 32 + lkh * 8;
            bh[nf] = *reinterpret_cast<const bf16x8_t*>(&BThi[off]);
            bl[nf] = *reinterpret_cast<const bf16x8_t*>(&BTlo[off]);
        }
        #pragma unroll
        for (int m = 0; m < 4; ++m)
            #pragma unroll
            for (int nf = 0; nf < 4; ++nf) {
                acc[m][nf] = __builtin_amdgcn_mfma_f32_16x16x32_bf16(ah[m], bh[nf], acc[m][nf], 0, 0, 0);
                acc[m][nf] = __builtin_amdgcn_mfma_f32_16x16x32_bf16(ah[m], bl[nf], acc[m][nf], 0, 0, 0);
                acc[m][nf] = __builtin_amdgcn_mfma_f32_16x16x32_bf16(al[m], bh[nf], acc[m][nf], 0, 0, 0);
            }
    }

    // epilogue: C[row][col], row = base + lkh*4 + r2, col = colbase + l15
    #pragma unroll
    for (int m = 0; m < 4; ++m) {
        int rbase = row0 + wr + m * 16 + lkh * 4;
        #pragma unroll
        for (int nf = 0; nf < 4; ++nf) {
            int col = col0 + wc + nf * 16 + l15;
            #pragma unroll
            for (int r2 = 0; r2 < 4; ++r2) {
                int row = rbase + r2;
                if (row < M) C[(size_t)row * Ncols + col] = acc[m][nf][r2];
            }
        }
    }
}

// out[node][:] = relu(sum_in hw[src]*w + hw[node]*norm_self + bias) -> bf16 hi/lo split
__global__ __launch_bounds__(256)
void gcn_agg(const float* __restrict__ hw, const int* __restrict__ row_ptr,
             const int* __restrict__ csr_src, const float* __restrict__ csr_w,
             const float* __restrict__ norm_self, const float* __restrict__ bias,
             u16* __restrict__ g_hi, u16* __restrict__ g_lo, int n) {
    int node = blockIdx.x * 8 + (threadIdx.x >> 5);
    int lane = threadIdx.x & 31;
    if (node >= n) return;
    const float4* hw4 = reinterpret_cast<const float4*>(hw);
    float4 self = hw4[(size_t)node * 32 + lane];
    float ns = norm_self[node];
    float4 a0, a1, a2, a3;
    a0.x = self.x * ns; a0.y = self.y * ns; a0.z = self.z * ns; a0.w = self.w * ns;
    a1 = make_float4(0.f, 0.f, 0.f, 0.f); a2 = a1; a3 = a1;
    int p  = row_ptr[node];
    int p1 = row_ptr[node + 1];
    for (; p + 4 <= p1; p += 4) {
        int s0 = csr_src[p], s1 = csr_src[p + 1], s2 = csr_src[p + 2], s3 = csr_src[p + 3];
        float w0 = csr_w[p], w1 = csr_w[p + 1], w2 = csr_w[p + 2], w3 = csr_w[p + 3];
        float4 v0 = hw4[(size_t)s0 * 32 + lane];
        float4 v1 = hw4[(size_t)s1 * 32 + lane];
        float4 v2 = hw4[(size_t)s2 * 32 + lane];
        float4 v3 = hw4[(size_t)s3 * 32 + lane];
        a0.x = fmaf(v0.x, w0, a0.x); a0.y = fmaf(v0.y, w0, a0.y);
        a0.z = fmaf(v0.z, w0, a0.z); a0.w = fmaf(v0.w, w0, a0.w);
        a1.x = fmaf(v1.x, w1, a1.x); a1.y = fmaf(v1.y, w1, a1.y);
        a1.z = fmaf(v1.z, w1, a1.z); a1.w = fmaf(v1.w, w1, a1.w);
        a2.x = fmaf(v2.x, w2, a2.x); a2.y = fmaf(v2.y, w2, a2.y);
        a2.z = fmaf(v2.z, w2, a2.z); a2.w = fmaf(v2.w, w2, a2.w);
        a3.x = fmaf(v3.x, w3, a3.x); a3.y = fmaf(v3.y, w3, a3.y);
        a3.z = fmaf(v3.z, w3, a3.z); a3.w = fmaf(v3.w, w3, a3.w);
    }
    for (; p < p1; ++p) {
        int s = csr_src[p];
        float w = csr_w[p];
        float4 v = hw4[(size_t)s * 32 + lane];
        a0.x = fmaf(v.x, w, a0.x); a0.y = fmaf(v.y, w, a0.y);
        a0.z = fmaf(v.z, w, a0.z); a0.w = fmaf(v.w, w, a0.w);
    }
    float4 b4 = reinterpret_cast<const float4*>(bias)[lane];
    float ox = fmaxf(a0.x + a1.x + a2.x + a3.x + b4.x, 0.0f);
    float oy = fmaxf(a0.y + a1.y + a2.y + a3.y + b4.y, 0.0f);
    float oz = fmaxf(a0.z + a1.z + a2.z + a3.z + b4.z, 0.0f);
    float ow = fmaxf(a0.w + a1.w + a2.w + a3.w + b4.w, 0.0f);
    ushort4 hv, lv;
    hv.x = f2b(ox); lv.x = f2b(ox - b2f(hv.x));
    hv.y = f2b(oy); lv.y = f2b(oy - b2f(hv.y));
    hv.z = f2b(oz); lv.z = f2b(oz - b2f(hv.z));
    hv.w = f2b(ow); lv.w = f2b(ow - b2f(hv.w));
    *reinterpret_cast<ushort4*>(&g_hi[(size_t)node * HID + lane * 4]) = hv;
    *reinterpret_cast<ushort4*>(&g_lo[(size_t)node * HID + lane * 4]) = lv;
}

__global__ __launch_bounds__(256)
void gru_kernel(const float* __restrict__ gi, const float* __restrict__ gh,
                const float* __restrict__ b_ih, const float* __restrict__ b_hh,
                float* __restrict__ h, u16* __restrict__ h_hi, u16* __restrict__ h_lo, int n) {
    int idx = blockIdx.x * 256 + threadIdx.x;     // one float4 of h per thread
    if (idx >= n * 32) return;
    int row = idx >> 5, q = idx & 31;
    const float4* gi4 = reinterpret_cast<const float4*>(gi + (size_t)row * H3);
    const float4* gh4 = reinterpret_cast<const float4*>(gh + (size_t)row * H3);
    const float4* bi4 = reinterpret_cast<const float4*>(b_ih);
    const float4* bh4 = reinterpret_cast<const float4*>(b_hh);
    float4 vir = gi4[q], viz = gi4[32 + q], vin = gi4[64 + q];
    float4 vhr = gh4[q], vhz = gh4[32 + q], vhn = gh4[64 + q];
    float4 bir = bi4[q], biz = bi4[32 + q], bin_ = bi4[64 + q];
    float4 bhr = bh4[q], bhz = bh4[32 + q], bhn = bh4[64 + q];
    float4* h4 = reinterpret_cast<float4*>(h);
    float4 hv = h4[idx];
    float4 o;
    {
        float r = sigmoidf_((vir.x + bir.x) + (vhr.x + bhr.x));
        float z = sigmoidf_((viz.x + biz.x) + (vhz.x + bhz.x));
        float nn2 = tanhf((vin.x + bin_.x) + r * (vhn.x + bhn.x));
        o.x = (1.0f - z) * nn2 + z * hv.x;
    }
    {
        float r = sigmoidf_((vir.y + bir.y) + (vhr.y + bhr.y));
        float z = sigmoidf_((viz.y + biz.y) + (vhz.y + bhz.y));
        float nn2 = tanhf((vin.y + bin_.y) + r * (vhn.y + bhn.y));
        o.y = (1.0f - z) * nn2 + z * hv.y;
    }
    {
        float r = sigmoidf_((vir.z + bir.z) + (vhr.z + bhr.z));
        float z = sigmoidf_((viz.z + biz.z) + (vhz.z + bhz.z));
        float nn2 = tanhf((vin.z + bin_.z) + r * (vhn.z + bhn.z));
        o.z = (1.0f - z) * nn2 + z * hv.z;
    }
    {
        float r = sigmoidf_((vir.w + bir.w) + (vhr.w + bhr.w));
        float z = sigmoidf_((viz.w + biz.w) + (vhz.w + bhz.w));
        float nn2 = tanhf((vin.w + bin_.w) + r * (vhn.w + bhn.w));
        o.w = (1.0f - z) * nn2 + z * hv.w;
    }
    h4[idx] = o;
    ushort4 hvv, lvv;
    hvv.x = f2b(o.x); lvv.x = f2b(o.x - b2f(hvv.x));
    hvv.y = f2b(o.y); lvv.y = f2b(o.y - b2f(hvv.y));
    hvv.z = f2b(o.z); lvv.z = f2b(o.z - b2f(hvv.z));
    hvv.w = f2b(o.w); lvv.w = f2b(o.w - b2f(hvv.w));
    *reinterpret_cast<ushort4*>(&h_hi[(size_t)row * HID + q * 4]) = hvv;
    *reinterpret_cast<ushort4*>(&h_lo[(size_t)row * HID + q * 4]) = lvv;
}

// ---------------- launcher ----------------

extern "C" void kernel_launch(void* const* d_in, const int* in_sizes, int n_in,
                              void* d_out, int out_size, void* d_ws, size_t ws_size,
                              hipStream_t stream) {
    const float* x        = (const float*)d_in[0];
    const float* edge_attr= (const float*)d_in[1];
    const float* W_lin    = (const float*)d_in[2];
    const float* b_lin    = (const float*)d_in[3];
    const float* Wc1      = (const float*)d_in[4];
    const float* bc1      = (const float*)d_in[5];
    const float* Wc2      = (const float*)d_in[6];
    const float* bc2      = (const float*)d_in[7];
    const float* W_ih     = (const float*)d_in[8];
    const float* b_ih     = (const float*)d_in[9];
    const float* W_hh     = (const float*)d_in[10];
    const float* b_hh     = (const float*)d_in[11];
    const float* Wf1      = (const float*)d_in[12];
    const float* bf1      = (const float*)d_in[13];
    const float* Wf2      = (const float*)d_in[14];
    const float* bf2      = (const float*)d_in[15];
    const float* Wg1      = (const float*)d_in[16];
    const float* bg1      = (const float*)d_in[17];
    const float* Wg2      = (const float*)d_in[18];
    const float* bg2      = (const float*)d_in[19];
    const int*   edge_index = (const int*)d_in[20];
    const int*   mask     = (const int*)d_in[21];

    const int n = in_sizes[21];       // 20000
    const int e = in_sizes[1];        // 320000
    const int* src = edge_index;
    const int* dst = edge_index + e;
    float* h = (float*)d_out;         // [n,128], GRU state (fp32)

    char* w = (char*)d_ws;
    auto alloc = [&](size_t bytes) -> char* {
        char* p = w;
        w += (bytes + 255) & ~(size_t)255;
        return p;
    };
    int*   first_eid = (int*)  alloc((size_t)n * 4);
    int*   deg_cnt   = (int*)  alloc((size_t)n * 4);
    int*   row_ptr   = (int*)  alloc((size_t)(n + 1) * 4);
    int*   fill_ptr  = (int*)  alloc((size_t)n * 4);
    float* dis       = (float*)alloc((size_t)n * 4);
    float* norm_self = (float*)alloc((size_t)n * 4);
    int*   first_out = (int*)  alloc((size_t)n * 4);
    float* first_dx  = (float*)alloc((size_t)n * 4);
    int*   d1_of     = (int*)  alloc((size_t)n * 4);
    int*   d2_of     = (int*)  alloc((size_t)n * 4);
    float* dxb_of    = (float*)alloc((size_t)n * 4);
    int*   csr_src   = (int*)  alloc((size_t)e * 4);
    float* csr_w     = (float*)alloc((size_t)e * 4);
    // bf16 split weight transposes BT[n][k]
    u16* Wc1T_hi = (u16*)alloc((size_t)HID * 128 * 2);
    u16* Wc1T_lo = (u16*)alloc((size_t)HID * 128 * 2);
    u16* Wc2T_hi = (u16*)alloc((size_t)HID * 128 * 2);
    u16* Wc2T_lo = (u16*)alloc((size_t)HID * 128 * 2);
    u16* WihT_hi = (u16*)alloc((size_t)H3 * 128 * 2);
    u16* WihT_lo = (u16*)alloc((size_t)H3 * 128 * 2);
    u16* WhhT_hi = (u16*)alloc((size_t)H3 * 128 * 2);
    u16* WhhT_lo = (u16*)alloc((size_t)H3 * 128 * 2);
    // activations
    u16*   g_hi  = (u16*)  alloc((size_t)n * HID * 2);
    u16*   g_lo  = (u16*)  alloc((size_t)n * HID * 2);
    u16*   h_hi  = (u16*)  alloc((size_t)n * HID * 2);
    u16*   h_lo  = (u16*)  alloc((size_t)n * HID * 2);
    float* bufH  = (float*)alloc((size_t)n * HID * 4);
    float* bufGi = (float*)alloc((size_t)n * H3 * 4);
    float* bufGh = (float*)alloc((size_t)n * H3 * 4);

    const int TPB = 256;
    dim3 gN((n + TPB - 1) / TPB), gE((e + TPB - 1) / TPB);

    // preprocessing (time-invariant)
    init_kernel<<<gN, TPB, 0, stream>>>(first_eid, deg_cnt, n);
    edge_pass1<<<gE, TPB, 0, stream>>>(src, dst, first_eid, deg_cnt, e);
    scan_kernel<<<1, 1024, 0, stream>>>(deg_cnt, row_ptr, fill_ptr, dis, norm_self, n);
    firsts_kernel<<<gN, TPB, 0, stream>>>(first_eid, dst, edge_attr, first_out, first_dx, n, e);
    edge_pass2<<<gE, TPB, 0, stream>>>(src, dst, fill_ptr, dis, csr_src, csr_w, e);
    ghost_kernel<<<gN, TPB, 0, stream>>>(mask, first_out, first_dx, d1_of, d2_of, dxb_of, n);
    wsplit_kernel<<<(HID * 128 + 255) / 256, TPB, 0, stream>>>(Wc1, Wc1T_hi, Wc1T_lo, HID);
    wsplit_kernel<<<(HID * 128 + 255) / 256, TPB, 0, stream>>>(Wc2, Wc2T_hi, Wc2T_lo, HID);
    wsplit_kernel<<<(H3 * 128 + 255) / 256, TPB, 0, stream>>>(W_ih, WihT_hi, WihT_lo, H3);
    wsplit_kernel<<<(H3 * 128 + 255) / 256, TPB, 0, stream>>>(W_hh, WhhT_hi, WhhT_lo, H3);

    // h0 = 0 (fp32 and split)
    zero_kernel<<<(n * HID + TPB - 1) / TPB, TPB, 0, stream>>>(h, n * HID);
    zero_kernel<<<(n * 64 + TPB - 1) / TPB, TPB, 0, stream>>>((float*)h_hi, n * 64);
    zero_kernel<<<(n * 64 + TPB - 1) / TPB, TPB, 0, stream>>>((float*)h_lo, n * 64);

    const int mblocks = (n + 127) / 128;
    dim3 grid_gcn(mblocks, 1, 1);
    dim3 grid_gru(mblocks, 3, 2);
    dim3 agg_grid((n + 7) / 8);

    for (int t = 0; t < T_IN; ++t) {
        fuse_lin_kernel<<<n, 128, 0, stream>>>(x, mask, d1_of, d2_of, dxb_of,
                                               Wf1, bf1, Wf2, bf2, Wg1, bg1, Wg2, bg2,
                                               W_lin, b_lin, g_hi, g_lo, t);
        // GCN layer 1: hw = g@Wc1 ; agg -> g (split)
        gemm_mfma<<<grid_gcn, 256, 0, stream>>>(g_hi, g_lo, Wc1T_hi, Wc1T_lo, bufH,
                                                g_hi, g_lo, Wc1T_hi, Wc1T_lo, bufH, n, HID);
        gcn_agg<<<agg_grid, 256, 0, stream>>>(bufH, row_ptr, csr_src, csr_w, norm_self, bc1,
                                              g_hi, g_lo, n);
        // GCN layer 2
        gemm_mfma<<<grid_gcn, 256, 0, stream>>>(g_hi, g_lo, Wc2T_hi, Wc2T_lo, bufH,
                                                g_hi, g_lo, Wc2T_hi, Wc2T_lo, bufH, n, HID);
        gcn_agg<<<agg_grid, 256, 0, stream>>>(bufH, row_ptr, csr_src, csr_w, norm_self, bc2,
                                              g_hi, g_lo, n);
        // GRU: gi = g@W_ih, gh = h@W_hh in one dispatch (blockIdx.z)
        gemm_mfma<<<grid_gru, 256, 0, stream>>>(g_hi, g_lo, WihT_hi, WihT_lo, bufGi,
                                                h_hi, h_lo, WhhT_hi, WhhT_lo, bufGh, n, H3);
        gru_kernel<<<(n * 32 + TPB - 1) / TPB, TPB, 0, stream>>>(bufGi, bufGh, b_ih, b_hh,
                                                                 h, h_hi, h_lo, n);
    }
}

// Round 5
// 1189.289 us; speedup vs baseline: 1.7894x; 1.0912x over previous
//
#include <hip/hip_runtime.h>
#include <math.h>

// Problem constants (match reference)
#define NN 20000
#define T_IN 8
#define FEAT 16
#define HID 128
#define H3 384
#define FUSER_IN 49
#define FUSER_H 96
#define GATE_H 48
#define ALPHA 0.5f

typedef unsigned short u16;
typedef __attribute__((ext_vector_type(8))) short bf16x8_t;
typedef __attribute__((ext_vector_type(4))) float f32x4_t;

__device__ __forceinline__ float sigmoidf_(float v) { return 1.0f / (1.0f + expf(-v)); }

// bf16 round-to-nearest-even (finite values only)
__device__ __forceinline__ u16 f2b(float v) {
    unsigned u = __float_as_uint(v);
    unsigned r = (u + 0x7fffu + ((u >> 16) & 1u)) >> 16;
    return (u16)r;
}
__device__ __forceinline__ float b2f(u16 u) { return __uint_as_float(((unsigned)u) << 16); }

// ---------------- preprocessing ----------------

__global__ void init_kernel(int* first_eid, int* deg_cnt, int n) {
    int i = blockIdx.x * 256 + threadIdx.x;
    if (i < n) { first_eid[i] = 0x7fffffff; deg_cnt[i] = 0; }
}

__global__ void edge_pass1(const int* __restrict__ src, const int* __restrict__ dst,
                           int* first_eid, int* deg_cnt, int e) {
    int i = blockIdx.x * 256 + threadIdx.x;
    if (i < e) {
        atomicMin(&first_eid[src[i]], i);
        atomicAdd(&deg_cnt[dst[i]], 1);
    }
}

// 3-phase parallel prefix sum over cnt[n] (n <= 256*256)
__global__ void scan1(const int* __restrict__ cnt, int* tmp, int* bsum, int n) {
    __shared__ int buf[256];
    int tid = threadIdx.x;
    int i = blockIdx.x * 256 + tid;
    int v = (i < n) ? cnt[i] : 0;
    buf[tid] = v;
    __syncthreads();
    #pragma unroll
    for (int off = 1; off < 256; off <<= 1) {
        int t = (tid >= off) ? buf[tid - off] : 0;
        __syncthreads();
        buf[tid] += t;
        __syncthreads();
    }
    if (i < n) tmp[i] = buf[tid];
    if (tid == 255) bsum[blockIdx.x] = buf[255];
}

__global__ void scan2(int* bsum, int nb) {
    __shared__ int buf[256];
    int tid = threadIdx.x;
    int v = (tid < nb) ? bsum[tid] : 0;
    buf[tid] = v;
    __syncthreads();
    #pragma unroll
    for (int off = 1; off < 256; off <<= 1) {
        int t = (tid >= off) ? buf[tid - off] : 0;
        __syncthreads();
        buf[tid] += t;
        __syncthreads();
    }
    if (tid < nb) bsum[tid] = buf[tid];   // inclusive block sums
}

__global__ void scan3(const int* __restrict__ cnt, const int* __restrict__ tmp,
                      const int* __restrict__ bsum,
                      int* row_ptr, int* fill_ptr, float* dis, float* norm_self, int n) {
    int i = blockIdx.x * 256 + threadIdx.x;
    if (i >= n) return;
    int pre = (blockIdx.x > 0) ? bsum[blockIdx.x - 1] : 0;
    int incl = tmp[i] + pre;
    int v = cnt[i];
    row_ptr[i + 1] = incl;
    fill_ptr[i] = incl - v;
    float deg = (float)v + 1.0f;
    dis[i] = 1.0f / sqrtf(deg);
    norm_self[i] = 1.0f / deg;
    if (i == 0) row_ptr[0] = 0;
}

__global__ void firsts_kernel(const int* __restrict__ first_eid, const int* __restrict__ dst,
                              const float* __restrict__ edge_attr,
                              int* first_out, float* first_dx, int n, int e) {
    int i = blockIdx.x * 256 + threadIdx.x;
    if (i >= n) return;
    int fe = first_eid[i];
    if (fe < e) {
        first_out[i] = dst[fe];
        first_dx[i] = fmaxf(edge_attr[fe], 1e-6f);
    } else {
        first_out[i] = -1;
        first_dx[i] = -1.0f;
    }
}

__global__ void edge_pass2(const int* __restrict__ src, const int* __restrict__ dst,
                           int* fill_ptr, const float* __restrict__ dis,
                           int* csr_src, float* csr_w, int e) {
    int i = blockIdx.x * 256 + threadIdx.x;
    if (i < e) {
        int d = dst[i], s = src[i];
        int pos = atomicAdd(&fill_ptr[d], 1);
        csr_src[pos] = s;
        csr_w[pos] = dis[s] * dis[d];
    }
}

__global__ void ghost_kernel(const int* __restrict__ mask, const int* __restrict__ first_out,
                             const float* __restrict__ first_dx,
                             int* d1_of, int* d2_of, float* dxb_of, int n) {
    int i = blockIdx.x * 256 + threadIdx.x;
    if (i >= n || mask[i] != 0) return;
    int b = first_out[i];
    float dxb = fmaxf(first_dx[i], 1e-6f);
    int d1, d2;
    if (b < 0) { d1 = i; d2 = i; }
    else {
        int n1 = first_out[b]; d1 = (n1 < 0) ? b : n1;
        int n2 = first_out[d1]; d2 = (n2 < 0) ? d1 : n2;
    }
    d1_of[i] = d1; d2_of[i] = d2; dxb_of[i] = dxb;
}

// zero two regions in one dispatch (grid-stride)
__global__ void zero2_kernel(float* a, int na, unsigned* b, int nb) {
    int stride = gridDim.x * 256;
    for (int i = blockIdx.x * 256 + threadIdx.x; i < na; i += stride) a[i] = 0.0f;
    for (int i = blockIdx.x * 256 + threadIdx.x; i < nb; i += stride) b[i] = 0u;
}

// W[k][nn] (K=128) -> BT_hi/BT_lo[nn][k] bf16 split, LDS-tiled transpose (coalesced both sides)
__global__ __launch_bounds__(256)
void wsplit_kernel(const float* __restrict__ W, u16* BT_hi, u16* BT_lo, int Ncols) {
    __shared__ float tile[32][33];
    int nb = blockIdx.x * 32;           // column-of-W (=row-of-BT) base
    int kb = blockIdx.y * 32;           // k base
    int tx = threadIdx.x & 31, ty = threadIdx.x >> 5;   // 32 x 8
    #pragma unroll
    for (int r = 0; r < 32; r += 8)
        tile[ty + r][tx] = W[(size_t)(kb + ty + r) * Ncols + nb + tx];
    __syncthreads();
    #pragma unroll
    for (int r = 0; r < 32; r += 8) {
        float v = tile[tx][ty + r];     // = W[kb+tx][nb+ty+r]
        u16 h = f2b(v);
        size_t off = (size_t)(nb + ty + r) * 128 + kb + tx;
        BT_hi[off] = h;
        BT_lo[off] = f2b(v - b2f(h));
    }
}

// ---------------- per-step kernels ----------------

// One block (128 threads) per node: ghost fusion (if ghost) + g = relu(x_fused @ W_lin + b_lin)
__global__ __launch_bounds__(128)
void fuse_lin_kernel(const float* __restrict__ x, const int* __restrict__ mask,
                     const int* __restrict__ d1_of, const int* __restrict__ d2_of,
                     const float* __restrict__ dxb_of,
                     const float* __restrict__ Wf1, const float* __restrict__ bf1,
                     const float* __restrict__ Wf2, const float* __restrict__ bf2,
                     const float* __restrict__ Wg1, const float* __restrict__ bg1,
                     const float* __restrict__ Wg2, const float* __restrict__ bg2,
                     const float* __restrict__ W_lin, const float* __restrict__ b_lin,
                     u16* __restrict__ g_hi, u16* __restrict__ g_lo, int t) {
    int i = blockIdx.x;
    int j = threadIdx.x;
    __shared__ float feats[FUSER_IN];
    __shared__ float xf[FEAT];
    __shared__ float z1[FUSER_H];
    __shared__ float zg[GATE_H];
    __shared__ float s_gate;

    const float* xrow = &x[(i * T_IN + t) * FEAT];
    if (j < FEAT) { float v = xrow[j]; feats[j] = v; xf[j] = v; }

    bool ghost = (mask[i] == 0);
    if (ghost) {
        if (j < FEAT) {
            int d1 = d1_of[i], d2 = d2_of[i];
            feats[FEAT + j]     = x[(d1 * T_IN + t) * FEAT + j];
            feats[2 * FEAT + j] = x[(d2 * T_IN + t) * FEAT + j];
        }
        if (j == 0) feats[3 * FEAT] = dxb_of[i];
        __syncthreads();
        if (j < FUSER_H) {
            float acc = bf1[j];
            for (int k = 0; k < FUSER_IN; ++k) acc = fmaf(feats[k], Wf1[k * FUSER_H + j], acc);
            z1[j] = fmaxf(acc, 0.0f);
        }
        if (j < GATE_H) {
            float acc = bg1[j];
            for (int k = 0; k < FUSER_IN; ++k) acc = fmaf(feats[k], Wg1[k * GATE_H + j], acc);
            zg[j] = fmaxf(acc, 0.0f);
        }
        __syncthreads();
        if (j == 0) {
            float s = bg2[0];
            for (int k = 0; k < GATE_H; ++k) s = fmaf(zg[k], Wg2[k], s);
            s_gate = sigmoidf_(s);
        }
        __syncthreads();
        if (j < FEAT) {
            float acc = bf2[j];
            for (int k = 0; k < FUSER_H; ++k) acc = fmaf(z1[k], Wf2[k * FEAT + j], acc);
            xf[j] = feats[j] + ALPHA * acc * s_gate;
        }
    }
    __syncthreads();
    float acc = b_lin[j];
    #pragma unroll
    for (int k = 0; k < FEAT; ++k) acc = fmaf(xf[k], W_lin[k * HID + j], acc);
    float v = fmaxf(acc, 0.0f);
    u16 hv = f2b(v);
    g_hi[(size_t)i * HID + j] = hv;
    g_lo[(size_t)i * HID + j] = f2b(v - b2f(hv));
}

// C[M x Ncols] (fp32) = A[M x 128] @ B[128 x Ncols] via bf16x3 split MFMA.
// BM in {64,128}, BN=128, 4 waves (2x2). K=128 fully in LDS (XOR-swizzled).
// EPI==1 additionally writes bf16(C) into Cb (for the gather in gcn_agg).
// blockIdx.z picks operand set 1 or 2 (two GEMMs per dispatch).
template<int BM, int EPI>
__global__ __launch_bounds__(256)
void gemm_mfma(const u16* __restrict__ Ahi1, const u16* __restrict__ Alo1,
               const u16* __restrict__ BThi1, const u16* __restrict__ BTlo1,
               float* __restrict__ C1, u16* __restrict__ Cb1,
               const u16* __restrict__ Ahi2, const u16* __restrict__ Alo2,
               const u16* __restrict__ BThi2, const u16* __restrict__ BTlo2,
               float* __restrict__ C2, u16* __restrict__ Cb2,
               int M, int Ncols) {
    __shared__ u16 ldsA[2][BM * 128];   // [hi/lo][row*128+k], XOR-swizzled
    const u16* Ahi  = blockIdx.z ? Ahi2  : Ahi1;
    const u16* Alo  = blockIdx.z ? Alo2  : Alo1;
    const u16* BThi = blockIdx.z ? BThi2 : BThi1;
    const u16* BTlo = blockIdx.z ? BTlo2 : BTlo1;
    float*     C    = blockIdx.z ? C2    : C1;
    u16*       Cb   = blockIdx.z ? Cb2   : Cb1;

    const int tid  = threadIdx.x;
    const int row0 = blockIdx.x * BM;
    const int col0 = blockIdx.y * 128;
    constexpr int MF = BM / 32;          // m-fragments per wave (wave tile BM/2 x 64)

    // stage A hi+lo: BM*16 16B-units per component
    #pragma unroll
    for (int it = 0; it < BM / 16; ++it) {
        int unit = tid + it * 256;
        int r = unit >> 4, s = unit & 15;
        int gr = row0 + r;
        uint4 vh = make_uint4(0, 0, 0, 0), vl = vh;
        if (gr < M) {
            vh = *reinterpret_cast<const uint4*>(&Ahi[(size_t)gr * 128 + s * 8]);
            vl = *reinterpret_cast<const uint4*>(&Alo[(size_t)gr * 128 + s * 8]);
        }
        int byte = (r * 256 + s * 16) ^ ((r & 7) << 4);
        *reinterpret_cast<uint4*>((char*)(&ldsA[0][0]) + byte) = vh;
        *reinterpret_cast<uint4*>((char*)(&ldsA[1][0]) + byte) = vl;
    }
    __syncthreads();

    const int wid  = tid >> 6;
    const int lane = tid & 63;
    const int wr = (wid >> 1) * (BM / 2);
    const int wc = (wid & 1) * 64;
    const int l15 = lane & 15;
    const int lkh = lane >> 4;          // k-chunk 0..3

    f32x4_t acc[MF][4] = {};

    #pragma unroll
    for (int kb = 0; kb < 4; ++kb) {
        bf16x8_t ah[MF], al[MF], bh[4], bl[4];
        #pragma unroll
        for (int m = 0; m < MF; ++m) {
            int row = wr + m * 16 + l15;
            int byte = (row * 256 + kb * 64 + lkh * 16) ^ ((row & 7) << 4);
            ah[m] = *reinterpret_cast<const bf16x8_t*>((const char*)(&ldsA[0][0]) + byte);
            al[m] = *reinterpret_cast<const bf16x8_t*>((const char*)(&ldsA[1][0]) + byte);
        }
        #pragma unroll
        for (int nf = 0; nf < 4; ++nf) {
            int col = col0 + wc + nf * 16 + l15;
            size_t off = (size_t)col * 128 + kb * 32 + lkh * 8;
            bh[nf] = *reinterpret_cast<const bf16x8_t*>(&BThi[off]);
            bl[nf] = *reinterpret_cast<const bf16x8_t*>(&BTlo[off]);
        }
        #pragma unroll
        for (int m = 0; m < MF; ++m)
            #pragma unroll
            for (int nf = 0; nf < 4; ++nf) {
                acc[m][nf] = __builtin_amdgcn_mfma_f32_16x16x32_bf16(ah[m], bh[nf], acc[m][nf], 0, 0, 0);
                acc[m][nf] = __builtin_amdgcn_mfma_f32_16x16x32_bf16(ah[m], bl[nf], acc[m][nf], 0, 0, 0);
                acc[m][nf] = __builtin_amdgcn_mfma_f32_16x16x32_bf16(al[m], bh[nf], acc[m][nf], 0, 0, 0);
            }
    }

    #pragma unroll
    for (int m = 0; m < MF; ++m) {
        int rbase = row0 + wr + m * 16 + lkh * 4;
        #pragma unroll
        for (int nf = 0; nf < 4; ++nf) {
            int col = col0 + wc + nf * 16 + l15;
            #pragma unroll
            for (int r2 = 0; r2 < 4; ++r2) {
                int row = rbase + r2;
                if (row < M) {
                    float v = acc[m][nf][r2];
                    C[(size_t)row * Ncols + col] = v;
                    if constexpr (EPI == 1) Cb[(size_t)row * Ncols + col] = f2b(v);
                }
            }
        }
    }
}

// out[node][:] = relu(sum_in bf16(hw[src])*w + hw[node]*norm_self + bias) -> bf16 hi/lo split
// 32 threads/node, gathers ushort4 (8B/lane, 256B/edge); self term fp32.
__global__ __launch_bounds__(256)
void gcn_agg(const float* __restrict__ hw, const u16* __restrict__ hwb,
             const int* __restrict__ row_ptr,
             const int* __restrict__ csr_src, const float* __restrict__ csr_w,
             const float* __restrict__ norm_self, const float* __restrict__ bias,
             u16* __restrict__ g_hi, u16* __restrict__ g_lo, int n) {
    int node = blockIdx.x * 8 + (threadIdx.x >> 5);
    int lane = threadIdx.x & 31;
    if (node >= n) return;
    const float4* hw4 = reinterpret_cast<const float4*>(hw);
    float4 self = hw4[(size_t)node * 32 + lane];
    float ns = norm_self[node];
    float4 a0, a1, a2, a3;
    a0.x = self.x * ns; a0.y = self.y * ns; a0.z = self.z * ns; a0.w = self.w * ns;
    a1 = make_float4(0.f, 0.f, 0.f, 0.f); a2 = a1; a3 = a1;
    int p  = row_ptr[node];
    int p1 = row_ptr[node + 1];
    for (; p + 4 <= p1; p += 4) {
        int s0 = csr_src[p], s1 = csr_src[p + 1], s2 = csr_src[p + 2], s3 = csr_src[p + 3];
        float w0 = csr_w[p], w1 = csr_w[p + 1], w2 = csr_w[p + 2], w3 = csr_w[p + 3];
        ushort4 v0 = *reinterpret_cast<const ushort4*>(&hwb[(size_t)s0 * HID + lane * 4]);
        ushort4 v1 = *reinterpret_cast<const ushort4*>(&hwb[(size_t)s1 * HID + lane * 4]);
        ushort4 v2 = *reinterpret_cast<const ushort4*>(&hwb[(size_t)s2 * HID + lane * 4]);
        ushort4 v3 = *reinterpret_cast<const ushort4*>(&hwb[(size_t)s3 * HID + lane * 4]);
        a0.x = fmaf(b2f(v0.x), w0, a0.x); a0.y = fmaf(b2f(v0.y), w0, a0.y);
        a0.z = fmaf(b2f(v0.z), w0, a0.z); a0.w = fmaf(b2f(v0.w), w0, a0.w);
        a1.x = fmaf(b2f(v1.x), w1, a1.x); a1.y = fmaf(b2f(v1.y), w1, a1.y);
        a1.z = fmaf(b2f(v1.z), w1, a1.z); a1.w = fmaf(b2f(v1.w), w1, a1.w);
        a2.x = fmaf(b2f(v2.x), w2, a2.x); a2.y = fmaf(b2f(v2.y), w2, a2.y);
        a2.z = fmaf(b2f(v2.z), w2, a2.z); a2.w = fmaf(b2f(v2.w), w2, a2.w);
        a3.x = fmaf(b2f(v3.x), w3, a3.x); a3.y = fmaf(b2f(v3.y), w3, a3.y);
        a3.z = fmaf(b2f(v3.z), w3, a3.z); a3.w = fmaf(b2f(v3.w), w3, a3.w);
    }
    for (; p < p1; ++p) {
        int s = csr_src[p];
        float w = csr_w[p];
        ushort4 v = *reinterpret_cast<const ushort4*>(&hwb[(size_t)s * HID + lane * 4]);
        a0.x = fmaf(b2f(v.x), w, a0.x); a0.y = fmaf(b2f(v.y), w, a0.y);
        a0.z = fmaf(b2f(v.z), w, a0.z); a0.w = fmaf(b2f(v.w), w, a0.w);
    }
    float4 b4 = reinterpret_cast<const float4*>(bias)[lane];
    float ox = fmaxf(a0.x + a1.x + a2.x + a3.x + b4.x, 0.0f);
    float oy = fmaxf(a0.y + a1.y + a2.y + a3.y + b4.y, 0.0f);
    float oz = fmaxf(a0.z + a1.z + a2.z + a3.z + b4.z, 0.0f);
    float ow = fmaxf(a0.w + a1.w + a2.w + a3.w + b4.w, 0.0f);
    ushort4 hv, lv;
    hv.x = f2b(ox); lv.x = f2b(ox - b2f(hv.x));
    hv.y = f2b(oy); lv.y = f2b(oy - b2f(hv.y));
    hv.z = f2b(oz); lv.z = f2b(oz - b2f(hv.z));
    hv.w = f2b(ow); lv.w = f2b(ow - b2f(hv.w));
    *reinterpret_cast<ushort4*>(&g_hi[(size_t)node * HID + lane * 4]) = hv;
    *reinterpret_cast<ushort4*>(&g_lo[(size_t)node * HID + lane * 4]) = lv;
}

__global__ __launch_bounds__(256)
void gru_kernel(const float* __restrict__ gi, const float* __restrict__ gh,
                const float* __restrict__ b_ih, const float* __restrict__ b_hh,
                float* __restrict__ h, u16* __restrict__ h_hi, u16* __restrict__ h_lo, int n) {
    int idx = blockIdx.x * 256 + threadIdx.x;     // one float4 of h per thread
    if (idx >= n * 32) return;
    int row = idx >> 5, q = idx & 31;
    const float4* gi4 = reinterpret_cast<const float4*>(gi + (size_t)row * H3);
    const float4* gh4 = reinterpret_cast<const float4*>(gh + (size_t)row * H3);
    const float4* bi4 = reinterpret_cast<const float4*>(b_ih);
    const float4* bh4 = reinterpret_cast<const float4*>(b_hh);
    float4 vir = gi4[q], viz = gi4[32 + q], vin = gi4[64 + q];
    float4 vhr = gh4[q], vhz = gh4[32 + q], vhn = gh4[64 + q];
    float4 bir = bi4[q], biz = bi4[32 + q], bin_ = bi4[64 + q];
    float4 bhr = bh4[q], bhz = bh4[32 + q], bhn = bh4[64 + q];
    float4* h4 = reinterpret_cast<float4*>(h);
    float4 hv = h4[idx];
    float4 o;
    {
        float r = sigmoidf_((vir.x + bir.x) + (vhr.x + bhr.x));
        float z = sigmoidf_((viz.x + biz.x) + (vhz.x + bhz.x));
        float nn2 = tanhf((vin.x + bin_.x) + r * (vhn.x + bhn.x));
        o.x = (1.0f - z) * nn2 + z * hv.x;
    }
    {
        float r = sigmoidf_((vir.y + bir.y) + (vhr.y + bhr.y));
        float z = sigmoidf_((viz.y + biz.y) + (vhz.y + bhz.y));
        float nn2 = tanhf((vin.y + bin_.y) + r * (vhn.y + bhn.y));
        o.y = (1.0f - z) * nn2 + z * hv.y;
    }
    {
        float r = sigmoidf_((vir.z + bir.z) + (vhr.z + bhr.z));
        float z = sigmoidf_((viz.z + biz.z) + (vhz.z + bhz.z));
        float nn2 = tanhf((vin.z + bin_.z) + r * (vhn.z + bhn.z));
        o.z = (1.0f - z) * nn2 + z * hv.z;
    }
    {
        float r = sigmoidf_((vir.w + bir.w) + (vhr.w + bhr.w));
        float z = sigmoidf_((viz.w + biz.w) + (vhz.w + bhz.w));
        float nn2 = tanhf((vin.w + bin_.w) + r * (vhn.w + bhn.w));
        o.w = (1.0f - z) * nn2 + z * hv.w;
    }
    h4[idx] = o;
    ushort4 hvv, lvv;
    hvv.x = f2b(o.x); lvv.x = f2b(o.x - b2f(hvv.x));
    hvv.y = f2b(o.y); lvv.y = f2b(o.y - b2f(hvv.y));
    hvv.z = f2b(o.z); lvv.z = f2b(o.z - b2f(hvv.z));
    hvv.w = f2b(o.w); lvv.w = f2b(o.w - b2f(hvv.w));
    *reinterpret_cast<ushort4*>(&h_hi[(size_t)row * HID + q * 4]) = hvv;
    *reinterpret_cast<ushort4*>(&h_lo[(size_t)row * HID + q * 4]) = lvv;
}

// ---------------- launcher ----------------

extern "C" void kernel_launch(void* const* d_in, const int* in_sizes, int n_in,
                              void* d_out, int out_size, void* d_ws, size_t ws_size,
                              hipStream_t stream) {
    const float* x        = (const float*)d_in[0];
    const float* edge_attr= (const float*)d_in[1];
    const float* W_lin    = (const float*)d_in[2];
    const float* b_lin    = (const float*)d_in[3];
    const float* Wc1      = (const float*)d_in[4];
    const float* bc1      = (const float*)d_in[5];
    const float* Wc2      = (const float*)d_in[6];
    const float* bc2      = (const float*)d_in[7];
    const float* W_ih     = (const float*)d_in[8];
    const float* b_ih     = (const float*)d_in[9];
    const float* W_hh     = (const float*)d_in[10];
    const float* b_hh     = (const float*)d_in[11];
    const float* Wf1      = (const float*)d_in[12];
    const float* bf1      = (const float*)d_in[13];
    const float* Wf2      = (const float*)d_in[14];
    const float* bf2      = (const float*)d_in[15];
    const float* Wg1      = (const float*)d_in[16];
    const float* bg1      = (const float*)d_in[17];
    const float* Wg2      = (const float*)d_in[18];
    const float* bg2      = (const float*)d_in[19];
    const int*   edge_index = (const int*)d_in[20];
    const int*   mask     = (const int*)d_in[21];

    const int n = in_sizes[21];       // 20000
    const int e = in_sizes[1];        // 320000
    const int* src = edge_index;
    const int* dst = edge_index + e;
    float* h = (float*)d_out;         // [n,128], GRU state (fp32)

    char* w = (char*)d_ws;
    auto alloc = [&](size_t bytes) -> char* {
        char* p = w;
        w += (bytes + 255) & ~(size_t)255;
        return p;
    };
    int*   first_eid = (int*)  alloc((size_t)n * 4);
    int*   deg_cnt   = (int*)  alloc((size_t)n * 4);
    int*   row_ptr   = (int*)  alloc((size_t)(n + 1) * 4);
    int*   fill_ptr  = (int*)  alloc((size_t)n * 4);
    int*   tmp_scan  = (int*)  alloc((size_t)n * 4);
    int*   bsum      = (int*)  alloc((size_t)256 * 4);
    float* dis       = (float*)alloc((size_t)n * 4);
    float* norm_self = (float*)alloc((size_t)n * 4);
    int*   first_out = (int*)  alloc((size_t)n * 4);
    float* first_dx  = (float*)alloc((size_t)n * 4);
    int*   d1_of     = (int*)  alloc((size_t)n * 4);
    int*   d2_of     = (int*)  alloc((size_t)n * 4);
    float* dxb_of    = (float*)alloc((size_t)n * 4);
    int*   csr_src   = (int*)  alloc((size_t)e * 4);
    float* csr_w     = (float*)alloc((size_t)e * 4);
    // bf16 split weight transposes BT[n][k]
    u16* Wc1T_hi = (u16*)alloc((size_t)HID * 128 * 2);
    u16* Wc1T_lo = (u16*)alloc((size_t)HID * 128 * 2);
    u16* Wc2T_hi = (u16*)alloc((size_t)HID * 128 * 2);
    u16* Wc2T_lo = (u16*)alloc((size_t)HID * 128 * 2);
    u16* WihT_hi = (u16*)alloc((size_t)H3 * 128 * 2);
    u16* WihT_lo = (u16*)alloc((size_t)H3 * 128 * 2);
    u16* WhhT_hi = (u16*)alloc((size_t)H3 * 128 * 2);
    u16* WhhT_lo = (u16*)alloc((size_t)H3 * 128 * 2);
    // activations
    u16*   g_hi  = (u16*)  alloc((size_t)n * HID * 2);
    u16*   g_lo  = (u16*)  alloc((size_t)n * HID * 2);
    u16*   h_hi  = (u16*)  alloc((size_t)n * HID * 2);   // adjacent to h_lo (sizes 256-aligned)
    u16*   h_lo  = (u16*)  alloc((size_t)n * HID * 2);
    float* bufH  = (float*)alloc((size_t)n * HID * 4);
    u16*   bufHb = (u16*)  alloc((size_t)n * HID * 2);
    float* bufGi = (float*)alloc((size_t)n * H3 * 4);
    float* bufGh = (float*)alloc((size_t)n * H3 * 4);

    const int TPB = 256;
    const int nb = (n + 255) / 256;
    dim3 gN(nb), gE((e + TPB - 1) / TPB);

    // preprocessing (time-invariant)
    init_kernel<<<gN, TPB, 0, stream>>>(first_eid, deg_cnt, n);
    edge_pass1<<<gE, TPB, 0, stream>>>(src, dst, first_eid, deg_cnt, e);
    scan1<<<gN, TPB, 0, stream>>>(deg_cnt, tmp_scan, bsum, n);
    scan2<<<1, TPB, 0, stream>>>(bsum, nb);
    scan3<<<gN, TPB, 0, stream>>>(deg_cnt, tmp_scan, bsum, row_ptr, fill_ptr, dis, norm_self, n);
    firsts_kernel<<<gN, TPB, 0, stream>>>(first_eid, dst, edge_attr, first_out, first_dx, n, e);
    edge_pass2<<<gE, TPB, 0, stream>>>(src, dst, fill_ptr, dis, csr_src, csr_w, e);
    ghost_kernel<<<gN, TPB, 0, stream>>>(mask, first_out, first_dx, d1_of, d2_of, dxb_of, n);
    wsplit_kernel<<<dim3(HID / 32, 4), TPB, 0, stream>>>(Wc1, Wc1T_hi, Wc1T_lo, HID);
    wsplit_kernel<<<dim3(HID / 32, 4), TPB, 0, stream>>>(Wc2, Wc2T_hi, Wc2T_lo, HID);
    wsplit_kernel<<<dim3(H3 / 32, 4), TPB, 0, stream>>>(W_ih, WihT_hi, WihT_lo, H3);
    wsplit_kernel<<<dim3(H3 / 32, 4), TPB, 0, stream>>>(W_hh, WhhT_hi, WhhT_lo, H3);

    // h0 = 0 (fp32) and split hi/lo (adjacent region, as u32 words)
    zero2_kernel<<<2048, TPB, 0, stream>>>(h, n * HID, (unsigned*)h_hi, n * HID);

    dim3 grid_gcn((n + 63) / 64, 1, 1);
    dim3 grid_gru((n + 127) / 128, 3, 2);
    dim3 agg_grid((n + 7) / 8);

    for (int t = 0; t < T_IN; ++t) {
        fuse_lin_kernel<<<n, 128, 0, stream>>>(x, mask, d1_of, d2_of, dxb_of,
                                               Wf1, bf1, Wf2, bf2, Wg1, bg1, Wg2, bg2,
                                               W_lin, b_lin, g_hi, g_lo, t);
        // GCN layer 1: hw = g@Wc1 (fp32 + bf16 copy); agg -> g (split)
        gemm_mfma<64, 1><<<grid_gcn, 256, 0, stream>>>(
            g_hi, g_lo, Wc1T_hi, Wc1T_lo, bufH, bufHb,
            g_hi, g_lo, Wc1T_hi, Wc1T_lo, bufH, bufHb, n, HID);
        gcn_agg<<<agg_grid, 256, 0, stream>>>(bufH, bufHb, row_ptr, csr_src, csr_w,
                                              norm_self, bc1, g_hi, g_lo, n);
        // GCN layer 2
        gemm_mfma<64, 1><<<grid_gcn, 256, 0, stream>>>(
            g_hi, g_lo, Wc2T_hi, Wc2T_lo, bufH, bufHb,
            g_hi, g_lo, Wc2T_hi, Wc2T_lo, bufH, bufHb, n, HID);
        gcn_agg<<<agg_grid, 256, 0, stream>>>(bufH, bufHb, row_ptr, csr_src, csr_w,
                                              norm_self, bc2, g_hi, g_lo, n);
        // GRU: gi = g@W_ih, gh = h@W_hh in one dispatch (blockIdx.z)
        gemm_mfma<128, 0><<<grid_gru, 256, 0, stream>>>(
            g_hi, g_lo, WihT_hi, WihT_lo, bufGi, (u16*)nullptr,
            h_hi, h_lo, WhhT_hi, WhhT_lo, bufGh, (u16*)nullptr, n, H3);
        gru_kernel<<<(n * 32 + TPB - 1) / TPB, TPB, 0, stream>>>(bufGi, bufGh, b_ih, b_hh,
                                                                 h, h_hi, h_lo, n);
    }
}